// Round 2
// baseline (353.470 us; speedup 1.0000x reference)
//
#include <hip/hip_runtime.h>

// SlidingWindowAttention: B=2, L=2048, D=1024, H=16, hd=64, W=256.
// I/O dtype: float32 (per reference). Internal compute: bf16 MFMA, f32 accum.
#define DIM 1024
#define NH  16
#define HD  64
#define BB  2
#define LL  2048
#define WIN 256

typedef __bf16 bf16x8 __attribute__((ext_vector_type(8)));
typedef float  f32x4  __attribute__((ext_vector_type(4)));
typedef unsigned short u16x8 __attribute__((ext_vector_type(8)));

__device__ __forceinline__ unsigned short f2bf(float f) {
    union { float f; unsigned int i; } v; v.f = f;
    unsigned int r = v.i + 0x7fffu + ((v.i >> 16) & 1u);  // RNE
    return (unsigned short)(r >> 16);
}
__device__ __forceinline__ bf16x8 load8bf(const unsigned short* p) {
    uint4 u = *reinterpret_cast<const uint4*>(p);
    return __builtin_bit_cast(bf16x8, u);
}
__device__ __forceinline__ bf16x8 load8f(const float* p) {
    // 8 consecutive f32 -> bf16x8 (RNE), two 16B loads
    u16x8 r;
    #pragma unroll
    for (int j = 0; j < 8; j++) r[j] = f2bf(p[j]);
    return __builtin_bit_cast(bf16x8, r);
}

// ---------------------------------------------------------------------------
// Kernel 1: fused QKV projection + RoPE. One wave (64 thr) per 64x64 tile.
// grid = (DIM/64, B*L/64, 3). z selects Wq/Wk/Wv. 64-col tile == one head.
// MFMA 16x16x32 bf16; verified layouts:
//   A[m][k]: m=lane&15, k=(lane>>4)*8+j
//   B[k][n]: n=lane&15, k=(lane>>4)*8+j   (W is [n][k] row-major -> contiguous)
//   D[r][c]: c=lane&15, r=(lane>>4)*4+reg
// RoPE partner (d +/- 32) = acc[mi][ni +/- 2], same lane/reg.
// Output layout: [B, H, L, 64] bf16 (workspace).
// ---------------------------------------------------------------------------
__global__ __launch_bounds__(64) void qkv_rope_gemm(
    const float* __restrict__ x,
    const float* __restrict__ Wq,
    const float* __restrict__ Wk,
    const float* __restrict__ Wv,
    const float* __restrict__ cosb,
    const float* __restrict__ sinb,
    unsigned short* __restrict__ qws,
    unsigned short* __restrict__ kws,
    unsigned short* __restrict__ vws)
{
    const int lane = threadIdx.x;
    const int n0   = blockIdx.x * 64;
    const int m0   = blockIdx.y * 64;
    const int which = blockIdx.z;
    const float* Wm     = (which == 0) ? Wq : (which == 1) ? Wk : Wv;
    unsigned short* dst = (which == 0) ? qws : (which == 1) ? kws : vws;

    const int lr   = lane & 15;
    const int quad = lane >> 4;
    const int ko   = quad * 8;

    f32x4 acc[4][4];
    for (int i = 0; i < 4; i++)
        for (int j = 0; j < 4; j++) acc[i][j] = 0.0f;

    const float* xa = x  + (size_t)(m0 + lr) * DIM + ko;
    const float* wb = Wm + (size_t)(n0 + lr) * DIM + ko;

    for (int k0 = 0; k0 < DIM; k0 += 32) {
        bf16x8 a[4], b[4];
        #pragma unroll
        for (int mi = 0; mi < 4; mi++) a[mi] = load8f(xa + (size_t)mi * 16 * DIM + k0);
        #pragma unroll
        for (int ni = 0; ni < 4; ni++) b[ni] = load8f(wb + (size_t)ni * 16 * DIM + k0);
        #pragma unroll
        for (int mi = 0; mi < 4; mi++)
            #pragma unroll
            for (int ni = 0; ni < 4; ni++)
                acc[mi][ni] = __builtin_amdgcn_mfma_f32_16x16x32_bf16(
                    a[mi], b[ni], acc[mi][ni], 0, 0, 0);
    }

    const int h = n0 >> 6;  // head index (tile spans exactly one head)
    #pragma unroll
    for (int mi = 0; mi < 4; mi++) {
        #pragma unroll
        for (int reg = 0; reg < 4; reg++) {
            const int row = m0 + mi * 16 + quad * 4 + reg;  // global token = b*L + l
            const int b = row >> 11;
            const int l = row & (LL - 1);
            #pragma unroll
            for (int ni = 0; ni < 4; ni++) {
                const int d = ni * 16 + lr;  // 0..63 within head
                float val = acc[mi][ni][reg];
                float outv;
                if (which != 2) {
                    const float c = cosb[l * HD + d];
                    const float s = sinb[l * HD + d];
                    const float partner = (d < 32) ? -acc[mi][ni + 2][reg]
                                                   :  acc[mi][ni - 2][reg];
                    outv = val * c + partner * s;
                } else {
                    outv = val;
                }
                dst[(((size_t)(b * NH + h)) * LL + l) * HD + d] = f2bf(outv);
            }
        }
    }
}

// ---------------------------------------------------------------------------
// Kernel 2: sliding-window attention. One wave per (b, h, 16-query tile).
// Window spans <= 272 keys (17 tiles of 16) -> full 16x272 score matrix in LDS.
// ---------------------------------------------------------------------------
#define MAXKP 288   // 272 padded up to multiple of 32
__global__ __launch_bounds__(64) void swa_attn(
    const unsigned short* __restrict__ qws,
    const unsigned short* __restrict__ kws,
    const unsigned short* __restrict__ vws,
    unsigned short* __restrict__ aout)
{
    __shared__ float S[16][MAXKP + 1];  // odd stride -> conflict-free columns
    __shared__ float inv_sum[16];

    const int lane = threadIdx.x;
    const int qt = blockIdx.x;   // 0..127
    const int h  = blockIdx.y;   // 0..15
    const int b  = blockIdx.z;   // 0..1
    const int i0 = qt * 16;
    const int j0 = max(0, i0 - WIN);     // multiple of 16
    const int nk = i0 + 16 - j0;         // #keys, multiple of 16, <= 272

    const int lr   = lane & 15;
    const int quad = lane >> 4;
    const int ko   = quad * 8;

    const size_t base = ((size_t)(b * NH + h)) * LL * HD;
    const unsigned short* Q = qws + base;
    const unsigned short* K = kws + base;
    const unsigned short* V = vws + base;

    // Q fragments (reused across all key tiles): rows i0..i0+15, dims 0..63
    const bf16x8 qa0 = load8bf(Q + (size_t)(i0 + lr) * HD + ko);
    const bf16x8 qa1 = load8bf(Q + (size_t)(i0 + lr) * HD + 32 + ko);

    // Phase 1: scores -> LDS (scaled + masked)
    const int ntile = nk >> 4;
    for (int kt = 0; kt < ntile; kt++) {
        const int jb = j0 + kt * 16;
        const bf16x8 kb0 = load8bf(K + (size_t)(jb + lr) * HD + ko);
        const bf16x8 kb1 = load8bf(K + (size_t)(jb + lr) * HD + 32 + ko);
        f32x4 sacc = 0.0f;
        sacc = __builtin_amdgcn_mfma_f32_16x16x32_bf16(qa0, kb0, sacc, 0, 0, 0);
        sacc = __builtin_amdgcn_mfma_f32_16x16x32_bf16(qa1, kb1, sacc, 0, 0, 0);
        #pragma unroll
        for (int reg = 0; reg < 4; reg++) {
            const int i = i0 + quad * 4 + reg;
            const int j = jb + lr;
            const bool valid = (j <= i) && (j >= i - WIN);
            S[quad * 4 + reg][kt * 16 + lr] = valid ? sacc[reg] * 0.125f : -3.0e38f;
        }
    }
    __syncthreads();

    // Phase 2: softmax (exp only; 1/sum folded into P later).
    const int nkp = (nk + 31) & ~31;
    {
        const int r = lane >> 2, p = lane & 3;
        float m = -3.4e38f;
        for (int c = p; c < nk; c += 4) m = fmaxf(m, S[r][c]);
        m = fmaxf(m, __shfl_xor(m, 1));
        m = fmaxf(m, __shfl_xor(m, 2));
        float sum = 0.f;
        for (int c = p; c < nk; c += 4) {
            const float e = __expf(S[r][c] - m);
            S[r][c] = e;
            sum += e;
        }
        sum += __shfl_xor(sum, 1);
        sum += __shfl_xor(sum, 2);
        if (p == 0) inv_sum[r] = 1.0f / sum;
        for (int c = nk + p; c < nkp; c += 4) S[r][c] = 0.f;  // zero-pad to x32
    }
    __syncthreads();

    // Phase 3: O = P @ V  (contraction over keys, 32 per MFMA)
    f32x4 o[4];
    #pragma unroll
    for (int nt = 0; nt < 4; nt++) o[nt] = 0.0f;
    const float isum = inv_sum[lr];  // A-frag row m = lr

    const int nchunk = nkp >> 5;
    for (int kc = 0; kc < nchunk; kc++) {
        u16x8 pa;
        #pragma unroll
        for (int j = 0; j < 8; j++)
            pa[j] = f2bf(S[lr][kc * 32 + ko + j] * isum);
        u16x8 bv[4];
        #pragma unroll
        for (int j = 0; j < 8; j++) {
            int jrow = j0 + kc * 32 + ko + j;
            jrow = min(jrow, LL - 1);        // P==0 beyond nk, value irrelevant
            const unsigned short* vr = V + (size_t)jrow * HD + lr;
            #pragma unroll
            for (int nt = 0; nt < 4; nt++) bv[nt][j] = vr[nt * 16];
        }
        #pragma unroll
        for (int nt = 0; nt < 4; nt++)
            o[nt] = __builtin_amdgcn_mfma_f32_16x16x32_bf16(
                __builtin_bit_cast(bf16x8, pa), __builtin_bit_cast(bf16x8, bv[nt]),
                o[nt], 0, 0, 0);
    }

    // Epilogue: write [B, L, H*hd] bf16 (already normalized)
    #pragma unroll
    for (int nt = 0; nt < 4; nt++) {
        #pragma unroll
        for (int reg = 0; reg < 4; reg++) {
            const int i = i0 + quad * 4 + reg;
            const int d = nt * 16 + lr;
            aout[((size_t)(b * LL + i)) * DIM + h * HD + d] = f2bf(o[nt][reg]);
        }
    }
}

// ---------------------------------------------------------------------------
// Kernel 3: output projection: out = attn @ Wo^T. f32 output.
// ---------------------------------------------------------------------------
__global__ __launch_bounds__(64) void out_gemm(
    const unsigned short* __restrict__ A,
    const float* __restrict__ Wo,
    float* __restrict__ out)
{
    const int lane = threadIdx.x;
    const int n0 = blockIdx.x * 64;
    const int m0 = blockIdx.y * 64;
    const int lr   = lane & 15;
    const int quad = lane >> 4;
    const int ko   = quad * 8;

    f32x4 acc[4][4];
    for (int i = 0; i < 4; i++)
        for (int j = 0; j < 4; j++) acc[i][j] = 0.0f;

    const unsigned short* xa = A  + (size_t)(m0 + lr) * DIM + ko;
    const float*          wb = Wo + (size_t)(n0 + lr) * DIM + ko;

    for (int k0 = 0; k0 < DIM; k0 += 32) {
        bf16x8 a[4], b[4];
        #pragma unroll
        for (int mi = 0; mi < 4; mi++) a[mi] = load8bf(xa + (size_t)mi * 16 * DIM + k0);
        #pragma unroll
        for (int ni = 0; ni < 4; ni++) b[ni] = load8f(wb + (size_t)ni * 16 * DIM + k0);
        #pragma unroll
        for (int mi = 0; mi < 4; mi++)
            #pragma unroll
            for (int ni = 0; ni < 4; ni++)
                acc[mi][ni] = __builtin_amdgcn_mfma_f32_16x16x32_bf16(
                    a[mi], b[ni], acc[mi][ni], 0, 0, 0);
    }

    #pragma unroll
    for (int mi = 0; mi < 4; mi++) {
        #pragma unroll
        for (int reg = 0; reg < 4; reg++) {
            const int row = m0 + mi * 16 + quad * 4 + reg;
            #pragma unroll
            for (int ni = 0; ni < 4; ni++) {
                const int col = n0 + ni * 16 + lr;
                out[(size_t)row * DIM + col] = acc[mi][ni][reg];
            }
        }
    }
}

extern "C" void kernel_launch(void* const* d_in, const int* in_sizes, int n_in,
                              void* d_out, int out_size, void* d_ws, size_t ws_size,
                              hipStream_t stream)
{
    const float* x    = (const float*)d_in[0];
    const float* cosb = (const float*)d_in[1];
    const float* sinb = (const float*)d_in[2];
    const float* Wq   = (const float*)d_in[3];
    const float* Wk   = (const float*)d_in[4];
    const float* Wv   = (const float*)d_in[5];
    const float* Wo   = (const float*)d_in[6];
    float* out = (float*)d_out;

    const size_t per = (size_t)BB * NH * LL * HD;  // 4 Mi elems = 8 MB bf16
    unsigned short* qws = (unsigned short*)d_ws;
    unsigned short* kws = qws + per;
    unsigned short* vws = kws + per;
    unsigned short* aws = vws + per;               // [B, L, D] bf16

    qkv_rope_gemm<<<dim3(DIM / 64, BB * LL / 64, 3), 64, 0, stream>>>(
        x, Wq, Wk, Wv, cosb, sinb, qws, kws, vws);
    swa_attn<<<dim3(LL / 16, NH, BB), 64, 0, stream>>>(qws, kws, vws, aws);
    out_gemm<<<dim3(DIM / 64, BB * LL / 64), 64, 0, stream>>>(aws, Wo, out);
}

// Round 3
// 219.012 us; speedup vs baseline: 1.6139x; 1.6139x over previous
//
#include <hip/hip_runtime.h>

// SlidingWindowAttention: B=2, L=2048, D=1024, H=16, hd=64, W=256.
// I/O f32; internal bf16 MFMA with f32 accum.
#define DIM 1024
#define NH  16
#define HD  64
#define BB  2
#define LL  2048
#define WIN 256
#define MM  (BB * LL)     // 4096 rows
#define NQKV (3 * DIM)    // 3072 fused QKV output cols
#define SEG  (DIM * DIM)  // 1048576 elements per weight matrix

typedef __bf16 bf16x8 __attribute__((ext_vector_type(8)));
typedef float  f32x4  __attribute__((ext_vector_type(4)));
typedef unsigned short u16x8 __attribute__((ext_vector_type(8)));

__device__ __forceinline__ unsigned short f2bf(float f) {
    union { float f; unsigned int i; } v; v.f = f;
    unsigned int r = v.i + 0x7fffu + ((v.i >> 16) & 1u);  // RNE
    return (unsigned short)(r >> 16);
}
__device__ __forceinline__ bf16x8 load8bf(const unsigned short* p) {
    uint4 u = *reinterpret_cast<const uint4*>(p);
    return __builtin_bit_cast(bf16x8, u);
}
__device__ __forceinline__ void gll16(const void* g, void* l) {
    __builtin_amdgcn_global_load_lds(
        (const __attribute__((address_space(1))) unsigned int*)g,
        (__attribute__((address_space(3))) unsigned int*)l, 16, 0, 0);
}

// ---------------------------------------------------------------------------
// Kernel 0: f32 -> bf16 conversion/packing. grid = (512, 8) x 256 thr.
// y 0..3: quarters of x -> xb ; y 4..6: Wq/Wk/Wv -> wqkv packed ; y 7: Wo -> wob
// ---------------------------------------------------------------------------
__global__ __launch_bounds__(256) void convert_inputs(
    const float* __restrict__ x,
    const float* __restrict__ Wq, const float* __restrict__ Wk,
    const float* __restrict__ Wv, const float* __restrict__ Wo,
    unsigned short* __restrict__ xb,
    unsigned short* __restrict__ wqkv,
    unsigned short* __restrict__ wob)
{
    const int y = blockIdx.y;
    const size_t base = ((size_t)blockIdx.x * 256 + threadIdx.x) * 8;
    const float* src; unsigned short* dst;
    if (y < 4)       { src = x + (size_t)y * SEG;  dst = xb + (size_t)y * SEG; }
    else if (y == 4) { src = Wq; dst = wqkv; }
    else if (y == 5) { src = Wk; dst = wqkv + SEG; }
    else if (y == 6) { src = Wv; dst = wqkv + 2 * (size_t)SEG; }
    else             { src = Wo; dst = wob; }
    float4 a = ((const float4*)(src + base))[0];
    float4 b = ((const float4*)(src + base))[1];
    u16x8 r;
    r[0] = f2bf(a.x); r[1] = f2bf(a.y); r[2] = f2bf(a.z); r[3] = f2bf(a.w);
    r[4] = f2bf(b.x); r[5] = f2bf(b.y); r[6] = f2bf(b.z); r[7] = f2bf(b.w);
    *(u16x8*)(dst + base) = r;
}

// ---------------------------------------------------------------------------
// Kernel 1: fused QKV GEMM + RoPE. m97-style: 128x128 tile, 4 waves (2x2),
// BK=32, global_load_lds width-16 staging, ds_read_b128 frags, 16 MFMA/step.
// Each wave owns 64 consecutive cols == one head of one of q/k/v.
// q,k -> [B,H,L,64] bf16 (RoPE fused); v -> TRANSPOSED [B,H,64,L] bf16.
// ---------------------------------------------------------------------------
__global__ __launch_bounds__(256) void qkv_gemm(
    const unsigned short* __restrict__ xb,
    const unsigned short* __restrict__ wqkv,
    const float* __restrict__ cosb, const float* __restrict__ sinb,
    unsigned short* __restrict__ qws, unsigned short* __restrict__ kws,
    unsigned short* __restrict__ vT)
{
    __shared__ __align__(16) unsigned short As[128 * 32];
    __shared__ __align__(16) unsigned short Bs[128 * 32];
    const int t = threadIdx.x;
    const int lane = t & 63, w = t >> 6;
    const int wm = w >> 1, wn = w & 1;
    const int lr = lane & 15, quad = lane >> 4, ko = quad * 8;
    const int n0 = blockIdx.x * 128, m0 = blockIdx.y * 128;

    f32x4 acc[4][4];
    for (int i = 0; i < 4; i++) for (int j = 0; j < 4; j++) acc[i][j] = 0.0f;

    const int arow = t >> 2, acol = (t & 3) * 8;  // staging map: t -> (row, col8)
    const unsigned short* ga = xb   + (size_t)(m0 + arow) * DIM + acol;
    const unsigned short* gb = wqkv + (size_t)(n0 + arow) * DIM + acol;
    unsigned short* la0 = &As[t * 8];
    unsigned short* la1 = &As[t * 8 + 2048];
    unsigned short* lb0 = &Bs[t * 8];
    unsigned short* lb1 = &Bs[t * 8 + 2048];

    for (int k0 = 0; k0 < DIM; k0 += 32) {
        __syncthreads();
        gll16(ga + k0,            la0);
        gll16(ga + 64 * DIM + k0, la1);
        gll16(gb + k0,            lb0);
        gll16(gb + 64 * DIM + k0, lb1);
        __syncthreads();
        bf16x8 af[4], bfr[4];
        #pragma unroll
        for (int mi = 0; mi < 4; mi++)
            af[mi] = load8bf(&As[(wm * 64 + mi * 16 + lr) * 32 + ko]);
        #pragma unroll
        for (int ni = 0; ni < 4; ni++)
            bfr[ni] = load8bf(&Bs[(wn * 64 + ni * 16 + lr) * 32 + ko]);
        #pragma unroll
        for (int mi = 0; mi < 4; mi++)
            #pragma unroll
            for (int ni = 0; ni < 4; ni++)
                acc[mi][ni] = __builtin_amdgcn_mfma_f32_16x16x32_bf16(
                    af[mi], bfr[ni], acc[mi][ni], 0, 0, 0);
    }

    const int ng = n0 + wn * 64;        // wave's global col base
    const int which = ng >> 10;         // 0=q 1=k 2=v (wave-uniform)
    const int h = (ng & (DIM - 1)) >> 6;
    #pragma unroll
    for (int mi = 0; mi < 4; mi++) {
        #pragma unroll
        for (int reg = 0; reg < 4; reg++) {
            const int row = m0 + wm * 64 + mi * 16 + quad * 4 + reg;
            const int b = row >> 11, l = row & (LL - 1);
            #pragma unroll
            for (int ni = 0; ni < 4; ni++) {
                const int d = ni * 16 + lr;
                const float val = acc[mi][ni][reg];
                if (which == 2) {
                    vT[((size_t)(b * NH + h) * HD + d) * LL + l] = f2bf(val);
                } else {
                    const float c = cosb[l * HD + d];
                    const float s = sinb[l * HD + d];
                    const float partner = (d < 32) ? -acc[mi][ni + 2][reg]
                                                   :  acc[mi][ni - 2][reg];
                    unsigned short o = f2bf(val * c + partner * s);
                    ((which == 0) ? qws : kws)
                        [((size_t)(b * NH + h) * LL + l) * HD + d] = o;
                }
            }
        }
    }
}

// ---------------------------------------------------------------------------
// Kernel 2: sliding-window attention. One wave per (b, h, 16-query tile).
// V read from transposed layout -> vector B-fragments.
// ---------------------------------------------------------------------------
#define MAXKP 288
__global__ __launch_bounds__(64) void swa_attn(
    const unsigned short* __restrict__ qws,
    const unsigned short* __restrict__ kws,
    const unsigned short* __restrict__ vT,
    unsigned short* __restrict__ aout)
{
    __shared__ float S[16][MAXKP + 1];
    __shared__ float inv_sum[16];

    const int lane = threadIdx.x;
    const int qt = blockIdx.x, h = blockIdx.y, b = blockIdx.z;
    const int i0 = qt * 16;
    const int j0 = max(0, i0 - WIN);
    const int nk = i0 + 16 - j0;              // multiple of 16, <= 272

    const int lr = lane & 15, quad = lane >> 4, ko = quad * 8;
    const size_t base = ((size_t)(b * NH + h)) * LL * HD;
    const unsigned short* Q  = qws + base;
    const unsigned short* K  = kws + base;
    const unsigned short* VT = vT + base;     // [64][LL]

    const bf16x8 qa0 = load8bf(Q + (size_t)(i0 + lr) * HD + ko);
    const bf16x8 qa1 = load8bf(Q + (size_t)(i0 + lr) * HD + 32 + ko);

    const int ntile = nk >> 4;
    for (int kt = 0; kt < ntile; kt++) {
        const int jb = j0 + kt * 16;
        const bf16x8 kb0 = load8bf(K + (size_t)(jb + lr) * HD + ko);
        const bf16x8 kb1 = load8bf(K + (size_t)(jb + lr) * HD + 32 + ko);
        f32x4 sacc = 0.0f;
        sacc = __builtin_amdgcn_mfma_f32_16x16x32_bf16(qa0, kb0, sacc, 0, 0, 0);
        sacc = __builtin_amdgcn_mfma_f32_16x16x32_bf16(qa1, kb1, sacc, 0, 0, 0);
        #pragma unroll
        for (int reg = 0; reg < 4; reg++) {
            const int i = i0 + quad * 4 + reg;
            const int j = jb + lr;
            const bool valid = (j <= i) && (j >= i - WIN);
            S[quad * 4 + reg][kt * 16 + lr] = valid ? sacc[reg] * 0.125f : -3.0e38f;
        }
    }
    __syncthreads();

    const int nkp = (nk + 31) & ~31;
    {
        const int r = lane >> 2, p = lane & 3;
        float m = -3.4e38f;
        for (int c = p; c < nk; c += 4) m = fmaxf(m, S[r][c]);
        m = fmaxf(m, __shfl_xor(m, 1));
        m = fmaxf(m, __shfl_xor(m, 2));
        float sum = 0.f;
        for (int c = p; c < nk; c += 4) {
            const float e = __expf(S[r][c] - m);
            S[r][c] = e;
            sum += e;
        }
        sum += __shfl_xor(sum, 1);
        sum += __shfl_xor(sum, 2);
        if (p == 0) inv_sum[r] = 1.0f / sum;
        for (int c = nk + p; c < nkp; c += 4) S[r][c] = 0.f;
    }
    __syncthreads();

    f32x4 o[4];
    #pragma unroll
    for (int nt = 0; nt < 4; nt++) o[nt] = 0.0f;
    const float isum = inv_sum[lr];

    const int nchunk = nkp >> 5;
    for (int kc = 0; kc < nchunk; kc++) {
        u16x8 pa;
        #pragma unroll
        for (int j = 0; j < 8; j++)
            pa[j] = f2bf(S[lr][kc * 32 + ko + j] * isum);
        int kbase = j0 + kc * 32 + ko;
        kbase = min(kbase, LL - 8);   // clamp touches only P==0 columns
        bf16x8 bv[4];
        #pragma unroll
        for (int nt = 0; nt < 4; nt++)
            bv[nt] = load8bf(VT + (size_t)(nt * 16 + lr) * LL + kbase);
        #pragma unroll
        for (int nt = 0; nt < 4; nt++)
            o[nt] = __builtin_amdgcn_mfma_f32_16x16x32_bf16(
                __builtin_bit_cast(bf16x8, pa), bv[nt], o[nt], 0, 0, 0);
    }

    #pragma unroll
    for (int nt = 0; nt < 4; nt++) {
        #pragma unroll
        for (int reg = 0; reg < 4; reg++) {
            const int i = i0 + quad * 4 + reg;
            const int d = nt * 16 + lr;
            aout[((size_t)(b * LL + i)) * DIM + h * HD + d] = f2bf(o[nt][reg]);
        }
    }
}

// ---------------------------------------------------------------------------
// Kernel 3: output projection, m97-style. A = attn (bf16), B = Wo (bf16),
// C = f32 out.
// ---------------------------------------------------------------------------
__global__ __launch_bounds__(256) void out_gemm(
    const unsigned short* __restrict__ A,
    const unsigned short* __restrict__ Wob,
    float* __restrict__ out)
{
    __shared__ __align__(16) unsigned short As[128 * 32];
    __shared__ __align__(16) unsigned short Bs[128 * 32];
    const int t = threadIdx.x;
    const int lane = t & 63, w = t >> 6;
    const int wm = w >> 1, wn = w & 1;
    const int lr = lane & 15, quad = lane >> 4, ko = quad * 8;
    const int n0 = blockIdx.x * 128, m0 = blockIdx.y * 128;

    f32x4 acc[4][4];
    for (int i = 0; i < 4; i++) for (int j = 0; j < 4; j++) acc[i][j] = 0.0f;

    const int arow = t >> 2, acol = (t & 3) * 8;
    const unsigned short* ga = A   + (size_t)(m0 + arow) * DIM + acol;
    const unsigned short* gb = Wob + (size_t)(n0 + arow) * DIM + acol;
    unsigned short* la0 = &As[t * 8];
    unsigned short* la1 = &As[t * 8 + 2048];
    unsigned short* lb0 = &Bs[t * 8];
    unsigned short* lb1 = &Bs[t * 8 + 2048];

    for (int k0 = 0; k0 < DIM; k0 += 32) {
        __syncthreads();
        gll16(ga + k0,            la0);
        gll16(ga + 64 * DIM + k0, la1);
        gll16(gb + k0,            lb0);
        gll16(gb + 64 * DIM + k0, lb1);
        __syncthreads();
        bf16x8 af[4], bfr[4];
        #pragma unroll
        for (int mi = 0; mi < 4; mi++)
            af[mi] = load8bf(&As[(wm * 64 + mi * 16 + lr) * 32 + ko]);
        #pragma unroll
        for (int ni = 0; ni < 4; ni++)
            bfr[ni] = load8bf(&Bs[(wn * 64 + ni * 16 + lr) * 32 + ko]);
        #pragma unroll
        for (int mi = 0; mi < 4; mi++)
            #pragma unroll
            for (int ni = 0; ni < 4; ni++)
                acc[mi][ni] = __builtin_amdgcn_mfma_f32_16x16x32_bf16(
                    af[mi], bfr[ni], acc[mi][ni], 0, 0, 0);
    }

    #pragma unroll
    for (int mi = 0; mi < 4; mi++) {
        #pragma unroll
        for (int reg = 0; reg < 4; reg++) {
            const int row = m0 + wm * 64 + mi * 16 + quad * 4 + reg;
            #pragma unroll
            for (int ni = 0; ni < 4; ni++) {
                const int col = n0 + wn * 64 + ni * 16 + lr;
                out[(size_t)row * DIM + col] = acc[mi][ni][reg];
            }
        }
    }
}

extern "C" void kernel_launch(void* const* d_in, const int* in_sizes, int n_in,
                              void* d_out, int out_size, void* d_ws, size_t ws_size,
                              hipStream_t stream)
{
    const float* x    = (const float*)d_in[0];
    const float* cosb = (const float*)d_in[1];
    const float* sinb = (const float*)d_in[2];
    const float* Wq   = (const float*)d_in[3];
    const float* Wk   = (const float*)d_in[4];
    const float* Wv   = (const float*)d_in[5];
    const float* Wo   = (const float*)d_in[6];
    float* out = (float*)d_out;

    // Workspace (u16 elems): xb 4.19M (reused as aws after qkv) | wqkv 3.15M |
    // wob 1.05M | qws 4.19M | kws 4.19M | vT 4.19M   => ~42 MB total
    unsigned short* xb   = (unsigned short*)d_ws;
    unsigned short* wqkv = xb + (size_t)MM * DIM;
    unsigned short* wob  = wqkv + (size_t)NQKV * DIM;
    unsigned short* qws  = wob + (size_t)DIM * DIM;
    unsigned short* kws  = qws + (size_t)BB * NH * LL * HD;
    unsigned short* vT   = kws + (size_t)BB * NH * LL * HD;
    unsigned short* aws  = xb;   // alias: xb dead after qkv_gemm

    convert_inputs<<<dim3(SEG / (256 * 8), 8), 256, 0, stream>>>(
        x, Wq, Wk, Wv, Wo, xb, wqkv, wob);
    qkv_gemm<<<dim3(NQKV / 128, MM / 128), 256, 0, stream>>>(
        xb, wqkv, cosb, sinb, qws, kws, vT);
    swa_attn<<<dim3(LL / 16, NH, BB), 64, 0, stream>>>(qws, kws, vT, aws);
    out_gemm<<<dim3(DIM / 128, MM / 128), 256, 0, stream>>>(aws, wob, out);
}

// Round 4
// 210.182 us; speedup vs baseline: 1.6817x; 1.0420x over previous
//
#include <hip/hip_runtime.h>

// SlidingWindowAttention: B=2, L=2048, D=1024, H=16, hd=64, W=256.
// I/O f32; internal bf16 MFMA with f32 accum.
#define DIM 1024
#define NH  16
#define HD  64
#define BB  2
#define LL  2048
#define WIN 256
#define MM  (BB * LL)     // 4096 rows
#define NQKV (3 * DIM)    // 3072 fused QKV output cols
#define SEG  (DIM * DIM)

typedef __bf16 bf16x8 __attribute__((ext_vector_type(8)));
typedef float  f32x4  __attribute__((ext_vector_type(4)));
typedef unsigned short u16x8 __attribute__((ext_vector_type(8)));

__device__ __forceinline__ unsigned short f2bf(float f) {
    union { float f; unsigned int i; } v; v.f = f;
    unsigned int r = v.i + 0x7fffu + ((v.i >> 16) & 1u);  // RNE
    return (unsigned short)(r >> 16);
}
__device__ __forceinline__ bf16x8 load8bf(const unsigned short* p) {
    uint4 u = *reinterpret_cast<const uint4*>(p);
    return __builtin_bit_cast(bf16x8, u);
}
__device__ __forceinline__ void gll16(const void* g, void* l) {
    __builtin_amdgcn_global_load_lds(
        (const __attribute__((address_space(1))) unsigned int*)g,
        (__attribute__((address_space(3))) unsigned int*)l, 16, 0, 0);
}

// ---------------------------------------------------------------------------
// Kernel 0: f32 -> bf16 conversion/packing.
// ---------------------------------------------------------------------------
__global__ __launch_bounds__(256) void convert_inputs(
    const float* __restrict__ x,
    const float* __restrict__ Wq, const float* __restrict__ Wk,
    const float* __restrict__ Wv, const float* __restrict__ Wo,
    unsigned short* __restrict__ xb,
    unsigned short* __restrict__ wqkv,
    unsigned short* __restrict__ wob)
{
    const int y = blockIdx.y;
    const size_t base = ((size_t)blockIdx.x * 256 + threadIdx.x) * 8;
    const float* src; unsigned short* dst;
    if (y < 4)       { src = x + (size_t)y * SEG;  dst = xb + (size_t)y * SEG; }
    else if (y == 4) { src = Wq; dst = wqkv; }
    else if (y == 5) { src = Wk; dst = wqkv + SEG; }
    else if (y == 6) { src = Wv; dst = wqkv + 2 * (size_t)SEG; }
    else             { src = Wo; dst = wob; }
    float4 a = ((const float4*)(src + base))[0];
    float4 b = ((const float4*)(src + base))[1];
    u16x8 r;
    r[0] = f2bf(a.x); r[1] = f2bf(a.y); r[2] = f2bf(a.z); r[3] = f2bf(a.w);
    r[4] = f2bf(b.x); r[5] = f2bf(b.y); r[6] = f2bf(b.z); r[7] = f2bf(b.w);
    *(u16x8*)(dst + base) = r;
}

// ---------------------------------------------------------------------------
// Kernel 1: fused QKV GEMM + RoPE. 128x128 tile, 4 waves (2x2), BK=64,
// global_load_lds width-16 with XOR-swizzled 8-elem chunks (conflict-free
// ds_read_b128 frags). Blocks are pure-q (bx<8), pure-k (8..15), pure-v (16+).
// q,k -> [B,H,L,64] (RoPE fused); v -> [B,H,64,L] via LDS transpose, 16B stores.
// ---------------------------------------------------------------------------
__global__ __launch_bounds__(256) void qkv_gemm(
    const unsigned short* __restrict__ xb,
    const unsigned short* __restrict__ wqkv,
    const float* __restrict__ cosb, const float* __restrict__ sinb,
    unsigned short* __restrict__ qws, unsigned short* __restrict__ kws,
    unsigned short* __restrict__ vT)
{
    __shared__ __align__(16) unsigned short smem[2 * 128 * 64];  // As | Bs, 32 KB
    unsigned short* As = smem;
    unsigned short* Bs = smem + 128 * 64;
    const int t = threadIdx.x;
    const int lane = t & 63, w = t >> 6;
    const int wm = w >> 1, wn = w & 1;
    const int lr = lane & 15, quad = lane >> 4;
    const int n0 = blockIdx.x * 128, m0 = blockIdx.y * 128;

    f32x4 acc[4][4];
    for (int i = 0; i < 4; i++) for (int j = 0; j < 4; j++) acc[i][j] = 0.0f;

    const int rsub  = lane >> 3;         // 0..7 row within 8-row stage
    const int chunk = (lane & 7) ^ rsub; // swizzled source chunk (of 8 elems)
    const int sw    = lr & 7;            // frag-read swizzle key (row&7)

    for (int k0 = 0; k0 < DIM; k0 += 64) {
        __syncthreads();
        #pragma unroll
        for (int it = 0; it < 4; it++) {
            const int row = (w * 4 + it) * 8 + rsub;
            gll16(xb   + (size_t)(m0 + row) * DIM + k0 + chunk * 8,
                  &As[(w * 4 + it) * 512 + lane * 8]);
            gll16(wqkv + (size_t)(n0 + row) * DIM + k0 + chunk * 8,
                  &Bs[(w * 4 + it) * 512 + lane * 8]);
        }
        __syncthreads();
        #pragma unroll
        for (int kk = 0; kk < 2; kk++) {
            bf16x8 af[4], bfr[4];
            #pragma unroll
            for (int mi = 0; mi < 4; mi++) {
                const int R = wm * 64 + mi * 16 + lr;
                af[mi] = load8bf(&As[R * 64 + (((kk * 4 + quad) ^ sw) * 8)]);
            }
            #pragma unroll
            for (int ni = 0; ni < 4; ni++) {
                const int R = wn * 64 + ni * 16 + lr;
                bfr[ni] = load8bf(&Bs[R * 64 + (((kk * 4 + quad) ^ sw) * 8)]);
            }
            #pragma unroll
            for (int mi = 0; mi < 4; mi++)
                #pragma unroll
                for (int ni = 0; ni < 4; ni++)
                    acc[mi][ni] = __builtin_amdgcn_mfma_f32_16x16x32_bf16(
                        af[mi], bfr[ni], acc[mi][ni], 0, 0, 0);
        }
    }

    const int ng = n0 + wn * 64;
    const int which = ng >> 10;            // 0=q 1=k 2=v (block-uniform here)
    const int h = (ng & (DIM - 1)) >> 6;

    if (which == 2) {
        // ---- v: transpose 64x64 tile through LDS, store 16B/lane to vT ----
        __syncthreads();                    // staging smem now dead
        unsigned short* T = smem + w * 4096;  // 64 rows(d) x 64 cols(l), dword-swizzled
        #pragma unroll
        for (int ni = 0; ni < 4; ni++) {
            const int d  = ni * 16 + lr;
            const int g4 = (d & 7) << 2;    // dword-swizzle key
            #pragma unroll
            for (int mi = 0; mi < 4; mi++)
                #pragma unroll
                for (int reg = 0; reg < 4; reg++) {
                    const int l = mi * 16 + quad * 4 + reg;
                    const int cw = (l >> 1) ^ g4;           // swizzled dword col
                    T[d * 64 + cw * 2 + (l & 1)] = f2bf(acc[mi][ni][reg]);
                }
        }
        __syncthreads();
        const int token0 = m0 + wm * 64;    // 64 tokens, same batch
        const int b  = token0 >> 11;
        const int lg = (token0 & (LL - 1)) + (lane & 7) * 8;
        #pragma unroll
        for (int s = 0; s < 8; s++) {
            const int d  = s * 8 + (lane >> 3);
            const int g4 = (d & 7) << 2;
            const int p  = ((lane & 7) * 4) ^ g4;           // swizzled dword pos
            uint4 val = *(const uint4*)&T[d * 64 + p * 2];
            *(uint4*)&vT[((size_t)(b * NH + h) * HD + d) * LL + lg] = val;
        }
    } else {
        // ---- q/k: fused RoPE epilogue ----
        unsigned short* dst = (which == 0) ? qws : kws;
        #pragma unroll
        for (int mi = 0; mi < 4; mi++) {
            #pragma unroll
            for (int reg = 0; reg < 4; reg++) {
                const int row = m0 + wm * 64 + mi * 16 + quad * 4 + reg;
                const int b = row >> 11, l = row & (LL - 1);
                #pragma unroll
                for (int ni = 0; ni < 4; ni++) {
                    const int d = ni * 16 + lr;
                    const float c = cosb[l * HD + d];
                    const float s = sinb[l * HD + d];
                    const float partner = (d < 32) ? -acc[mi][ni + 2][reg]
                                                   :  acc[mi][ni - 2][reg];
                    dst[((size_t)(b * NH + h) * LL + l) * HD + d] =
                        f2bf(acc[mi][ni][reg] * c + partner * s);
                }
            }
        }
    }
}

// ---------------------------------------------------------------------------
// Kernel 2: sliding-window attention. One wave per (b, h, 16-query tile).
// exp applied at C-layout (no max-shift; scores O(1)); P stored bf16 in LDS;
// row-sums kept in registers via shfl butterflies; 1/sum folded into epilogue.
// ---------------------------------------------------------------------------
#define SSTRIDE 296   // u16; rows 16B-aligned; Δrow bank shift 20 -> 2-way max
__global__ __launch_bounds__(64) void swa_attn(
    const unsigned short* __restrict__ qws,
    const unsigned short* __restrict__ kws,
    const unsigned short* __restrict__ vT,
    unsigned short* __restrict__ aout)
{
    __shared__ __align__(16) unsigned short Sb[16 * SSTRIDE];  // bf16 P

    const int lane = threadIdx.x;
    const int qt = blockIdx.x, h = blockIdx.y, b = blockIdx.z;
    const int i0 = qt * 16;
    const int j0 = max(0, i0 - WIN);
    const int nk = i0 + 16 - j0;              // multiple of 16, <= 272

    const int lr = lane & 15, quad = lane >> 4, ko = quad * 8;
    const size_t base = ((size_t)(b * NH + h)) * LL * HD;
    const unsigned short* Q  = qws + base;
    const unsigned short* K  = kws + base;
    const unsigned short* VT = vT + base;     // [64][LL]

    const bf16x8 qa0 = load8bf(Q + (size_t)(i0 + lr) * HD + ko);
    const bf16x8 qa1 = load8bf(Q + (size_t)(i0 + lr) * HD + 32 + ko);

    float rowsum[4] = {0.f, 0.f, 0.f, 0.f};  // row = quad*4+reg, partial over lr

    const int ntile = nk >> 4;
    for (int kt = 0; kt < ntile; kt++) {
        const int jb = j0 + kt * 16;
        const bf16x8 kb0 = load8bf(K + (size_t)(jb + lr) * HD + ko);
        const bf16x8 kb1 = load8bf(K + (size_t)(jb + lr) * HD + 32 + ko);
        f32x4 sacc = 0.0f;
        sacc = __builtin_amdgcn_mfma_f32_16x16x32_bf16(qa0, kb0, sacc, 0, 0, 0);
        sacc = __builtin_amdgcn_mfma_f32_16x16x32_bf16(qa1, kb1, sacc, 0, 0, 0);
        #pragma unroll
        for (int reg = 0; reg < 4; reg++) {
            const int i = i0 + quad * 4 + reg;
            const int j = jb + lr;
            const bool valid = (j <= i) && (j >= i - WIN);
            const float e = valid ? __expf(sacc[reg] * 0.125f) : 0.0f;
            rowsum[reg] += e;
            Sb[(quad * 4 + reg) * SSTRIDE + kt * 16 + lr] = f2bf(e);
        }
    }
    const int nkp = (nk + 31) & ~31;
    if (nk < nkp) {                            // zero-pad 16 columns
        #pragma unroll
        for (int r = 0; r < 4; r++)
            Sb[(quad * 4 + r) * SSTRIDE + nk + lr] = 0;
    }
    float inv[4];
    #pragma unroll
    for (int reg = 0; reg < 4; reg++) {        // 16-lane butterfly within quad
        float s = rowsum[reg];
        s += __shfl_xor(s, 1); s += __shfl_xor(s, 2);
        s += __shfl_xor(s, 4); s += __shfl_xor(s, 8);
        inv[reg] = 1.0f / s;                   // all lanes hold row quad*4+reg sum
    }
    __syncthreads();

    f32x4 o[4];
    #pragma unroll
    for (int nt = 0; nt < 4; nt++) o[nt] = 0.0f;

    const int nchunk = nkp >> 5;
    for (int kc = 0; kc < nchunk; kc++) {
        const bf16x8 pa = load8bf(&Sb[lr * SSTRIDE + kc * 32 + ko]);
        int kbase = j0 + kc * 32 + ko;
        kbase = min(kbase, LL - 8);            // clamp only touches P==0 cols
        bf16x8 bv[4];
        #pragma unroll
        for (int nt = 0; nt < 4; nt++)
            bv[nt] = load8bf(VT + (size_t)(nt * 16 + lr) * LL + kbase);
        #pragma unroll
        for (int nt = 0; nt < 4; nt++)
            o[nt] = __builtin_amdgcn_mfma_f32_16x16x32_bf16(pa, bv[nt], o[nt], 0, 0, 0);
    }

    #pragma unroll
    for (int nt = 0; nt < 4; nt++) {
        #pragma unroll
        for (int reg = 0; reg < 4; reg++) {
            const int i = i0 + quad * 4 + reg;
            const int d = nt * 16 + lr;
            aout[((size_t)(b * LL + i)) * DIM + h * HD + d] =
                f2bf(o[nt][reg] * inv[reg]);
        }
    }
}

// ---------------------------------------------------------------------------
// Kernel 3: output projection. 128(M)x64(N) tiles -> 512 blocks (2/CU),
// BK=64 + swizzled staging. Wave = 64M x 32N.
// ---------------------------------------------------------------------------
__global__ __launch_bounds__(256) void out_gemm(
    const unsigned short* __restrict__ A,
    const unsigned short* __restrict__ Wob,
    float* __restrict__ out)
{
    __shared__ __align__(16) unsigned short smem[128 * 64 + 64 * 64];  // 24 KB
    unsigned short* As = smem;
    unsigned short* Bs = smem + 128 * 64;
    const int t = threadIdx.x;
    const int lane = t & 63, w = t >> 6;
    const int wm = w >> 1, wn = w & 1;
    const int lr = lane & 15, quad = lane >> 4;
    const int n0 = blockIdx.x * 64, m0 = blockIdx.y * 128;

    f32x4 acc[4][2];
    for (int i = 0; i < 4; i++) for (int j = 0; j < 2; j++) acc[i][j] = 0.0f;

    const int rsub  = lane >> 3;
    const int chunk = (lane & 7) ^ rsub;
    const int sw    = lr & 7;

    for (int k0 = 0; k0 < DIM; k0 += 64) {
        __syncthreads();
        #pragma unroll
        for (int it = 0; it < 4; it++) {
            const int row = (w * 4 + it) * 8 + rsub;
            gll16(A + (size_t)(m0 + row) * DIM + k0 + chunk * 8,
                  &As[(w * 4 + it) * 512 + lane * 8]);
        }
        #pragma unroll
        for (int it = 0; it < 2; it++) {
            const int row = (w * 2 + it) * 8 + rsub;
            gll16(Wob + (size_t)(n0 + row) * DIM + k0 + chunk * 8,
                  &Bs[(w * 2 + it) * 512 + lane * 8]);
        }
        __syncthreads();
        #pragma unroll
        for (int kk = 0; kk < 2; kk++) {
            bf16x8 af[4], bfr[2];
            #pragma unroll
            for (int mi = 0; mi < 4; mi++) {
                const int R = wm * 64 + mi * 16 + lr;
                af[mi] = load8bf(&As[R * 64 + (((kk * 4 + quad) ^ sw) * 8)]);
            }
            #pragma unroll
            for (int ni = 0; ni < 2; ni++) {
                const int R = wn * 32 + ni * 16 + lr;
                bfr[ni] = load8bf(&Bs[R * 64 + (((kk * 4 + quad) ^ sw) * 8)]);
            }
            #pragma unroll
            for (int mi = 0; mi < 4; mi++)
                #pragma unroll
                for (int ni = 0; ni < 2; ni++)
                    acc[mi][ni] = __builtin_amdgcn_mfma_f32_16x16x32_bf16(
                        af[mi], bfr[ni], acc[mi][ni], 0, 0, 0);
        }
    }

    #pragma unroll
    for (int mi = 0; mi < 4; mi++) {
        #pragma unroll
        for (int reg = 0; reg < 4; reg++) {
            const int row = m0 + wm * 64 + mi * 16 + quad * 4 + reg;
            #pragma unroll
            for (int ni = 0; ni < 2; ni++) {
                const int col = n0 + wn * 32 + ni * 16 + lr;
                out[(size_t)row * DIM + col] = acc[mi][ni][reg];
            }
        }
    }
}

extern "C" void kernel_launch(void* const* d_in, const int* in_sizes, int n_in,
                              void* d_out, int out_size, void* d_ws, size_t ws_size,
                              hipStream_t stream)
{
    const float* x    = (const float*)d_in[0];
    const float* cosb = (const float*)d_in[1];
    const float* sinb = (const float*)d_in[2];
    const float* Wq   = (const float*)d_in[3];
    const float* Wk   = (const float*)d_in[4];
    const float* Wv   = (const float*)d_in[5];
    const float* Wo   = (const float*)d_in[6];
    float* out = (float*)d_out;

    unsigned short* xb   = (unsigned short*)d_ws;
    unsigned short* wqkv = xb + (size_t)MM * DIM;
    unsigned short* wob  = wqkv + (size_t)NQKV * DIM;
    unsigned short* qws  = wob + (size_t)DIM * DIM;
    unsigned short* kws  = qws + (size_t)BB * NH * LL * HD;
    unsigned short* vT   = kws + (size_t)BB * NH * LL * HD;
    unsigned short* aws  = xb;   // alias: xb dead after qkv_gemm

    convert_inputs<<<dim3(SEG / (256 * 8), 8), 256, 0, stream>>>(
        x, Wq, Wk, Wv, Wo, xb, wqkv, wob);
    qkv_gemm<<<dim3(NQKV / 128, MM / 128), 256, 0, stream>>>(
        xb, wqkv, cosb, sinb, qws, kws, vT);
    swa_attn<<<dim3(LL / 16, NH, BB), 64, 0, stream>>>(qws, kws, vT, aws);
    out_gemm<<<dim3(DIM / 64, MM / 128), 256, 0, stream>>>(aws, wob, out);
}

// Round 5
// 193.847 us; speedup vs baseline: 1.8234x; 1.0843x over previous
//
#include <hip/hip_runtime.h>

// SlidingWindowAttention: B=2, L=2048, D=1024, H=16, hd=64, W=256.
// I/O f32; internal bf16 MFMA with f32 accum.
#define DIM 1024
#define NH  16
#define HD  64
#define BB  2
#define LL  2048
#define WIN 256
#define MM  (BB * LL)     // 4096 rows
#define NQKV (3 * DIM)    // 3072 fused QKV output cols
#define SEG  (DIM * DIM)

typedef __bf16 bf16x8 __attribute__((ext_vector_type(8)));
typedef float  f32x4  __attribute__((ext_vector_type(4)));
typedef unsigned short u16x8 __attribute__((ext_vector_type(8)));

__device__ __forceinline__ unsigned short f2bf(float f) {
    union { float f; unsigned int i; } v; v.f = f;
    unsigned int r = v.i + 0x7fffu + ((v.i >> 16) & 1u);  // RNE
    return (unsigned short)(r >> 16);
}
__device__ __forceinline__ bf16x8 load8bf(const unsigned short* p) {
    uint4 u = *reinterpret_cast<const uint4*>(p);
    return __builtin_bit_cast(bf16x8, u);
}
__device__ __forceinline__ void gll16(const void* g, void* l) {
    __builtin_amdgcn_global_load_lds(
        (const __attribute__((address_space(1))) unsigned int*)g,
        (__attribute__((address_space(3))) unsigned int*)l, 16, 0, 0);
}

// ---------------------------------------------------------------------------
// Kernel 0: f32 -> bf16 conversion/packing.
// ---------------------------------------------------------------------------
__global__ __launch_bounds__(256) void convert_inputs(
    const float* __restrict__ x,
    const float* __restrict__ Wq, const float* __restrict__ Wk,
    const float* __restrict__ Wv, const float* __restrict__ Wo,
    unsigned short* __restrict__ xb,
    unsigned short* __restrict__ wqkv,
    unsigned short* __restrict__ wob)
{
    const int y = blockIdx.y;
    const size_t base = ((size_t)blockIdx.x * 256 + threadIdx.x) * 8;
    const float* src; unsigned short* dst;
    if (y < 4)       { src = x + (size_t)y * SEG;  dst = xb + (size_t)y * SEG; }
    else if (y == 4) { src = Wq; dst = wqkv; }
    else if (y == 5) { src = Wk; dst = wqkv + SEG; }
    else if (y == 6) { src = Wv; dst = wqkv + 2 * (size_t)SEG; }
    else             { src = Wo; dst = wob; }
    float4 a = ((const float4*)(src + base))[0];
    float4 b = ((const float4*)(src + base))[1];
    u16x8 r;
    r[0] = f2bf(a.x); r[1] = f2bf(a.y); r[2] = f2bf(a.z); r[3] = f2bf(a.w);
    r[4] = f2bf(b.x); r[5] = f2bf(b.y); r[6] = f2bf(b.z); r[7] = f2bf(b.w);
    *(u16x8*)(dst + base) = r;
}

// ---------------------------------------------------------------------------
// Kernel 1: fused QKV GEMM + RoPE. 128x128 tile, 4 waves (2x2), BK=32
// (VGPR ~76 -> 4 waves/SIMD; BK=64's 132 VGPR crossed the 128 cliff).
// XOR chunk-swizzle on staging: As[R][c] holds global chunk c ^ ((R>>1)&3)
// -> ds_read_b128 frags are 2-way (free). Blocks are pure q/k/v by bx.
// q,k -> [B,H,L,64] (RoPE fused); v -> [B,H,64,L] via 2-pass LDS transpose.
// ---------------------------------------------------------------------------
__global__ __launch_bounds__(256) void qkv_gemm(
    const unsigned short* __restrict__ xb,
    const unsigned short* __restrict__ wqkv,
    const float* __restrict__ cosb, const float* __restrict__ sinb,
    unsigned short* __restrict__ qws, unsigned short* __restrict__ kws,
    unsigned short* __restrict__ vT)
{
    __shared__ __align__(16) unsigned short smem[128 * 32 * 2];  // As|Bs 16 KB
    unsigned short* As = smem;
    unsigned short* Bs = smem + 128 * 32;
    const int t = threadIdx.x;
    const int lane = t & 63, w = t >> 6;
    const int wm = w >> 1, wn = w & 1;
    const int lr = lane & 15, quad = lane >> 4;
    const int n0 = blockIdx.x * 128, m0 = blockIdx.y * 128;

    f32x4 acc[4][4];
    for (int i = 0; i < 4; i++) for (int j = 0; j < 4; j++) acc[i][j] = 0.0f;

    const int arow = t >> 2;                               // 0..63
    const int scol = (((t & 3) ^ ((t >> 3) & 3))) * 8;     // swizzled src chunk
    const unsigned short* ga = xb   + (size_t)(m0 + arow) * DIM + scol;
    const unsigned short* gb = wqkv + (size_t)(n0 + arow) * DIM + scol;
    unsigned short* la0 = &As[t * 8];
    unsigned short* la1 = &As[t * 8 + 2048];
    unsigned short* lb0 = &Bs[t * 8];
    unsigned short* lb1 = &Bs[t * 8 + 2048];

    const int sw = (lr >> 1) & 3;   // frag-read swizzle key

    for (int k0 = 0; k0 < DIM; k0 += 32) {
        __syncthreads();
        gll16(ga + k0,            la0);
        gll16(ga + 64 * DIM + k0, la1);
        gll16(gb + k0,            lb0);
        gll16(gb + 64 * DIM + k0, lb1);
        __syncthreads();
        bf16x8 af[4], bfr[4];
        #pragma unroll
        for (int mi = 0; mi < 4; mi++)
            af[mi] = load8bf(&As[(wm * 64 + mi * 16 + lr) * 32 + (quad ^ sw) * 8]);
        #pragma unroll
        for (int ni = 0; ni < 4; ni++)
            bfr[ni] = load8bf(&Bs[(wn * 64 + ni * 16 + lr) * 32 + (quad ^ sw) * 8]);
        #pragma unroll
        for (int mi = 0; mi < 4; mi++)
            #pragma unroll
            for (int ni = 0; ni < 4; ni++)
                acc[mi][ni] = __builtin_amdgcn_mfma_f32_16x16x32_bf16(
                    af[mi], bfr[ni], acc[mi][ni], 0, 0, 0);
    }

    const int ng = n0 + wn * 64;
    const int which = ng >> 10;            // 0=q 1=k 2=v (block-uniform)
    const int h = (ng & (DIM - 1)) >> 6;

    if (which == 2) {
        // ---- v: transpose 64x64 tile -> vT[B,H,64,L], 2 passes of 32 d-rows
        __syncthreads();                   // staging smem now dead (block-wide)
        unsigned short* T = smem + w * 2048;      // 32 d-rows x 64 l-cols
        const int token0 = m0 + wm * 64;
        const int b  = token0 >> 11;
        const int lg = (token0 & (LL - 1)) + (lane & 7) * 8;
        #pragma unroll
        for (int p = 0; p < 2; p++) {
            #pragma unroll
            for (int ni = 2 * p; ni < 2 * p + 2; ni++) {
                const int dl = (ni & 1) * 16 + lr;        // 0..31
                const int g4 = (dl & 7) << 2;
                #pragma unroll
                for (int mi = 0; mi < 4; mi++)
                    #pragma unroll
                    for (int reg = 0; reg < 4; reg++) {
                        const int l = mi * 16 + quad * 4 + reg;
                        const int cw = (l >> 1) ^ g4;
                        T[dl * 64 + cw * 2 + (l & 1)] = f2bf(acc[mi][ni][reg]);
                    }
            }
            // wave-local RAW through LDS: compiler orders via lgkmcnt
            #pragma unroll
            for (int s = 0; s < 4; s++) {
                const int dl = s * 8 + (lane >> 3);
                const int d  = p * 32 + dl;
                const int g4 = (dl & 7) << 2;
                const int pd = ((lane & 7) * 4) ^ g4;
                uint4 val = *(const uint4*)&T[dl * 64 + pd * 2];
                *(uint4*)&vT[((size_t)(b * NH + h) * HD + d) * LL + lg] = val;
            }
        }
    } else {
        // ---- q/k: fused RoPE epilogue ----
        unsigned short* dst = (which == 0) ? qws : kws;
        #pragma unroll
        for (int mi = 0; mi < 4; mi++) {
            #pragma unroll
            for (int reg = 0; reg < 4; reg++) {
                const int row = m0 + wm * 64 + mi * 16 + quad * 4 + reg;
                const int b = row >> 11, l = row & (LL - 1);
                #pragma unroll
                for (int ni = 0; ni < 4; ni++) {
                    const int d = ni * 16 + lr;
                    const float c = cosb[l * HD + d];
                    const float s = sinb[l * HD + d];
                    const float partner = (d < 32) ? -acc[mi][ni + 2][reg]
                                                   :  acc[mi][ni - 2][reg];
                    dst[((size_t)(b * NH + h) * LL + l) * HD + d] =
                        f2bf(acc[mi][ni][reg] * c + partner * s);
                }
            }
        }
    }
}

// ---------------------------------------------------------------------------
// Kernel 2: sliding-window attention. One wave per (b, h, 16-query tile).
// FIXED trip counts (17 K-tiles / 9 PV-chunks) via span anchor SS=i0-256 and
// j>=0 masking -> full unroll -> batched load issue (latency hiding via ILP).
// exp at C-layout, P bf16 in LDS, 1/sum folded into epilogue.
// ---------------------------------------------------------------------------
#define SSTRIDE 296   // u16; 16B-aligned rows; frag reads land 2-way (free)
__global__ __launch_bounds__(64, 4) void swa_attn(
    const unsigned short* __restrict__ qws,
    const unsigned short* __restrict__ kws,
    const unsigned short* __restrict__ vT,
    unsigned short* __restrict__ aout)
{
    __shared__ __align__(16) unsigned short Sb[16 * SSTRIDE];  // bf16 P

    const int lane = threadIdx.x;
    const int qt = blockIdx.x, h = blockIdx.y, b = blockIdx.z;
    const int i0 = qt * 16;
    const int SS = i0 - WIN;                  // span start (may be < 0)

    const int lr = lane & 15, quad = lane >> 4, ko = quad * 8;
    const size_t base = ((size_t)(b * NH + h)) * LL * HD;
    const unsigned short* Q  = qws + base;
    const unsigned short* K  = kws + base;
    const unsigned short* VT = vT + base;     // [64][LL]

    const bf16x8 qa0 = load8bf(Q + (size_t)(i0 + lr) * HD + ko);
    const bf16x8 qa1 = load8bf(Q + (size_t)(i0 + lr) * HD + 32 + ko);

    float rowsum[4] = {0.f, 0.f, 0.f, 0.f};

    #pragma unroll
    for (int kt = 0; kt < 17; kt++) {
        const int jb = SS + kt * 16;
        const int jr = max(jb + lr, 0);       // clamped load row
        const bf16x8 kb0 = load8bf(K + (size_t)jr * HD + ko);
        const bf16x8 kb1 = load8bf(K + (size_t)jr * HD + 32 + ko);
        f32x4 sacc = 0.0f;
        sacc = __builtin_amdgcn_mfma_f32_16x16x32_bf16(qa0, kb0, sacc, 0, 0, 0);
        sacc = __builtin_amdgcn_mfma_f32_16x16x32_bf16(qa1, kb1, sacc, 0, 0, 0);
        #pragma unroll
        for (int reg = 0; reg < 4; reg++) {
            const int i = i0 + quad * 4 + reg;
            const int j = jb + lr;
            const bool valid = (j >= 0) && (j <= i) && (j >= i - WIN);
            const float e = valid ? __expf(sacc[reg] * 0.125f) : 0.0f;
            rowsum[reg] += e;
            Sb[(quad * 4 + reg) * SSTRIDE + kt * 16 + lr] = f2bf(e);
        }
    }
    // zero-pad columns [272, 288)
    #pragma unroll
    for (int r = 0; r < 4; r++)
        Sb[(quad * 4 + r) * SSTRIDE + 272 + lr] = 0;

    float inv[4];
    #pragma unroll
    for (int reg = 0; reg < 4; reg++) {       // 16-lane butterfly
        float s = rowsum[reg];
        s += __shfl_xor(s, 1); s += __shfl_xor(s, 2);
        s += __shfl_xor(s, 4); s += __shfl_xor(s, 8);
        inv[reg] = 1.0f / s;
    }
    __syncthreads();

    f32x4 o[4];
    #pragma unroll
    for (int nt = 0; nt < 4; nt++) o[nt] = 0.0f;

    #pragma unroll
    for (int kc = 0; kc < 9; kc++) {
        const bf16x8 pa = load8bf(&Sb[lr * SSTRIDE + kc * 32 + ko]);
        int kb = SS + kc * 32 + ko;
        kb = min(max(kb, 0), LL - 8);         // clamp touches only P==0 cols
        bf16x8 bv[4];
        #pragma unroll
        for (int nt = 0; nt < 4; nt++)
            bv[nt] = load8bf(VT + (size_t)(nt * 16 + lr) * LL + kb);
        #pragma unroll
        for (int nt = 0; nt < 4; nt++)
            o[nt] = __builtin_amdgcn_mfma_f32_16x16x32_bf16(pa, bv[nt], o[nt], 0, 0, 0);
    }

    #pragma unroll
    for (int nt = 0; nt < 4; nt++) {
        #pragma unroll
        for (int reg = 0; reg < 4; reg++) {
            const int i = i0 + quad * 4 + reg;
            const int d = nt * 16 + lr;
            aout[((size_t)(b * LL + i)) * DIM + h * HD + d] =
                f2bf(o[nt][reg] * inv[reg]);
        }
    }
}

// ---------------------------------------------------------------------------
// Kernel 3: output projection. 128(M)x64(N) tiles -> 512 blocks, BK=32 +
// swizzled staging. Wave = 64M x 32N.
// ---------------------------------------------------------------------------
__global__ __launch_bounds__(256) void out_gemm(
    const unsigned short* __restrict__ A,
    const unsigned short* __restrict__ Wob,
    float* __restrict__ out)
{
    __shared__ __align__(16) unsigned short smem[128 * 32 + 64 * 32];  // 12 KB
    unsigned short* As = smem;
    unsigned short* Bs = smem + 128 * 32;
    const int t = threadIdx.x;
    const int lane = t & 63, w = t >> 6;
    const int wm = w >> 1, wn = w & 1;
    const int lr = lane & 15, quad = lane >> 4;
    const int n0 = blockIdx.x * 64, m0 = blockIdx.y * 128;

    f32x4 acc[4][2];
    for (int i = 0; i < 4; i++) for (int j = 0; j < 2; j++) acc[i][j] = 0.0f;

    const int arow = t >> 2;
    const int scol = (((t & 3) ^ ((t >> 3) & 3))) * 8;
    const unsigned short* ga = A   + (size_t)(m0 + arow) * DIM + scol;
    const unsigned short* gb = Wob + (size_t)(n0 + arow) * DIM + scol;
    unsigned short* la0 = &As[t * 8];
    unsigned short* la1 = &As[t * 8 + 2048];
    unsigned short* lb0 = &Bs[t * 8];

    const int sw = (lr >> 1) & 3;

    for (int k0 = 0; k0 < DIM; k0 += 32) {
        __syncthreads();
        gll16(ga + k0,            la0);
        gll16(ga + 64 * DIM + k0, la1);
        gll16(gb + k0,            lb0);
        __syncthreads();
        bf16x8 af[4], bfr[2];
        #pragma unroll
        for (int mi = 0; mi < 4; mi++)
            af[mi] = load8bf(&As[(wm * 64 + mi * 16 + lr) * 32 + (quad ^ sw) * 8]);
        #pragma unroll
        for (int ni = 0; ni < 2; ni++)
            bfr[ni] = load8bf(&Bs[(wn * 32 + ni * 16 + lr) * 32 + (quad ^ sw) * 8]);
        #pragma unroll
        for (int mi = 0; mi < 4; mi++)
            #pragma unroll
            for (int ni = 0; ni < 2; ni++)
                acc[mi][ni] = __builtin_amdgcn_mfma_f32_16x16x32_bf16(
                    af[mi], bfr[ni], acc[mi][ni], 0, 0, 0);
    }

    #pragma unroll
    for (int mi = 0; mi < 4; mi++) {
        #pragma unroll
        for (int reg = 0; reg < 4; reg++) {
            const int row = m0 + wm * 64 + mi * 16 + quad * 4 + reg;
            #pragma unroll
            for (int ni = 0; ni < 2; ni++) {
                const int col = n0 + wn * 32 + ni * 16 + lr;
                out[(size_t)row * DIM + col] = acc[mi][ni][reg];
            }
        }
    }
}

extern "C" void kernel_launch(void* const* d_in, const int* in_sizes, int n_in,
                              void* d_out, int out_size, void* d_ws, size_t ws_size,
                              hipStream_t stream)
{
    const float* x    = (const float*)d_in[0];
    const float* cosb = (const float*)d_in[1];
    const float* sinb = (const float*)d_in[2];
    const float* Wq   = (const float*)d_in[3];
    const float* Wk   = (const float*)d_in[4];
    const float* Wv   = (const float*)d_in[5];
    const float* Wo   = (const float*)d_in[6];
    float* out = (float*)d_out;

    unsigned short* xb   = (unsigned short*)d_ws;
    unsigned short* wqkv = xb + (size_t)MM * DIM;
    unsigned short* wob  = wqkv + (size_t)NQKV * DIM;
    unsigned short* qws  = wob + (size_t)DIM * DIM;
    unsigned short* kws  = qws + (size_t)BB * NH * LL * HD;
    unsigned short* vT   = kws + (size_t)BB * NH * LL * HD;
    unsigned short* aws  = xb;   // alias: xb dead after qkv_gemm

    convert_inputs<<<dim3(SEG / (256 * 8), 8), 256, 0, stream>>>(
        x, Wq, Wk, Wv, Wo, xb, wqkv, wob);
    qkv_gemm<<<dim3(NQKV / 128, MM / 128), 256, 0, stream>>>(
        xb, wqkv, cosb, sinb, qws, kws, vT);
    swa_attn<<<dim3(LL / 16, NH, BB), 64, 0, stream>>>(qws, kws, vT, aws);
    out_gemm<<<dim3(DIM / 64, MM / 128), 256, 0, stream>>>(aws, wob, out);
}

// Round 6
// 181.482 us; speedup vs baseline: 1.9477x; 1.0681x over previous
//
#include <hip/hip_runtime.h>

// SlidingWindowAttention: B=2, L=2048, D=1024, H=16, hd=64, W=256.
// I/O f32; internal bf16 MFMA with f32 accum.
#define DIM 1024
#define NH  16
#define HD  64
#define BB  2
#define LL  2048
#define WIN 256
#define MM  (BB * LL)     // 4096 rows
#define NQKV (3 * DIM)    // 3072 fused QKV output cols
#define SEG  (DIM * DIM)

typedef __bf16 bf16x8 __attribute__((ext_vector_type(8)));
typedef float  f32x4  __attribute__((ext_vector_type(4)));
typedef unsigned short u16x8 __attribute__((ext_vector_type(8)));

__device__ __forceinline__ unsigned short f2bf(float f) {
    union { float f; unsigned int i; } v; v.f = f;
    unsigned int r = v.i + 0x7fffu + ((v.i >> 16) & 1u);  // RNE
    return (unsigned short)(r >> 16);
}
__device__ __forceinline__ bf16x8 load8bf(const unsigned short* p) {
    uint4 u = *reinterpret_cast<const uint4*>(p);
    return __builtin_bit_cast(bf16x8, u);
}
__device__ __forceinline__ void gll16(const void* g, void* l) {
    __builtin_amdgcn_global_load_lds(
        (const __attribute__((address_space(1))) unsigned int*)g,
        (__attribute__((address_space(3))) unsigned int*)l, 16, 0, 0);
}

// ---------------------------------------------------------------------------
// Kernel 0: f32 -> bf16 conversion/packing.
// ---------------------------------------------------------------------------
__global__ __launch_bounds__(256) void convert_inputs(
    const float* __restrict__ x,
    const float* __restrict__ Wq, const float* __restrict__ Wk,
    const float* __restrict__ Wv, const float* __restrict__ Wo,
    unsigned short* __restrict__ xb,
    unsigned short* __restrict__ wqkv,
    unsigned short* __restrict__ wob)
{
    const int y = blockIdx.y;
    const size_t base = ((size_t)blockIdx.x * 256 + threadIdx.x) * 8;
    const float* src; unsigned short* dst;
    if (y < 4)       { src = x + (size_t)y * SEG;  dst = xb + (size_t)y * SEG; }
    else if (y == 4) { src = Wq; dst = wqkv; }
    else if (y == 5) { src = Wk; dst = wqkv + SEG; }
    else if (y == 6) { src = Wv; dst = wqkv + 2 * (size_t)SEG; }
    else             { src = Wo; dst = wob; }
    float4 a = ((const float4*)(src + base))[0];
    float4 b = ((const float4*)(src + base))[1];
    u16x8 r;
    r[0] = f2bf(a.x); r[1] = f2bf(a.y); r[2] = f2bf(a.z); r[3] = f2bf(a.w);
    r[4] = f2bf(b.x); r[5] = f2bf(b.y); r[6] = f2bf(b.z); r[7] = f2bf(b.w);
    *(u16x8*)(dst + base) = r;
}

// ---------------------------------------------------------------------------
// Kernel 1: fused QKV GEMM + RoPE. 128x128 tile, 4 waves (2x2), BK=32,
// XOR chunk-swizzled staging (conflict-free ds_read_b128 frags).
// q,k -> [B,H,L,64] (RoPE fused); v -> [B,H,64,L] via 2-pass LDS transpose.
// ---------------------------------------------------------------------------
__global__ __launch_bounds__(256) void qkv_gemm(
    const unsigned short* __restrict__ xb,
    const unsigned short* __restrict__ wqkv,
    const float* __restrict__ cosb, const float* __restrict__ sinb,
    unsigned short* __restrict__ qws, unsigned short* __restrict__ kws,
    unsigned short* __restrict__ vT)
{
    __shared__ __align__(16) unsigned short smem[128 * 32 * 2];  // As|Bs 16 KB
    unsigned short* As = smem;
    unsigned short* Bs = smem + 128 * 32;
    const int t = threadIdx.x;
    const int lane = t & 63, w = t >> 6;
    const int wm = w >> 1, wn = w & 1;
    const int lr = lane & 15, quad = lane >> 4;
    const int n0 = blockIdx.x * 128, m0 = blockIdx.y * 128;

    f32x4 acc[4][4];
    for (int i = 0; i < 4; i++) for (int j = 0; j < 4; j++) acc[i][j] = 0.0f;

    const int arow = t >> 2;
    const int scol = (((t & 3) ^ ((t >> 3) & 3))) * 8;
    const unsigned short* ga = xb   + (size_t)(m0 + arow) * DIM + scol;
    const unsigned short* gb = wqkv + (size_t)(n0 + arow) * DIM + scol;
    unsigned short* la0 = &As[t * 8];
    unsigned short* la1 = &As[t * 8 + 2048];
    unsigned short* lb0 = &Bs[t * 8];
    unsigned short* lb1 = &Bs[t * 8 + 2048];

    const int sw = (lr >> 1) & 3;

    for (int k0 = 0; k0 < DIM; k0 += 32) {
        __syncthreads();
        gll16(ga + k0,            la0);
        gll16(ga + 64 * DIM + k0, la1);
        gll16(gb + k0,            lb0);
        gll16(gb + 64 * DIM + k0, lb1);
        __syncthreads();
        bf16x8 af[4], bfr[4];
        #pragma unroll
        for (int mi = 0; mi < 4; mi++)
            af[mi] = load8bf(&As[(wm * 64 + mi * 16 + lr) * 32 + (quad ^ sw) * 8]);
        #pragma unroll
        for (int ni = 0; ni < 4; ni++)
            bfr[ni] = load8bf(&Bs[(wn * 64 + ni * 16 + lr) * 32 + (quad ^ sw) * 8]);
        #pragma unroll
        for (int mi = 0; mi < 4; mi++)
            #pragma unroll
            for (int ni = 0; ni < 4; ni++)
                acc[mi][ni] = __builtin_amdgcn_mfma_f32_16x16x32_bf16(
                    af[mi], bfr[ni], acc[mi][ni], 0, 0, 0);
    }

    const int ng = n0 + wn * 64;
    const int which = ng >> 10;            // 0=q 1=k 2=v (block-uniform)
    const int h = (ng & (DIM - 1)) >> 6;

    if (which == 2) {
        // ---- v: transpose 64x64 tile -> vT[B,H,64,L], 2 passes of 32 d-rows
        __syncthreads();
        unsigned short* T = smem + w * 2048;
        const int token0 = m0 + wm * 64;
        const int b  = token0 >> 11;
        const int lg = (token0 & (LL - 1)) + (lane & 7) * 8;
        #pragma unroll
        for (int p = 0; p < 2; p++) {
            #pragma unroll
            for (int ni = 2 * p; ni < 2 * p + 2; ni++) {
                const int dl = (ni & 1) * 16 + lr;
                const int g4 = (dl & 7) << 2;
                #pragma unroll
                for (int mi = 0; mi < 4; mi++)
                    #pragma unroll
                    for (int reg = 0; reg < 4; reg++) {
                        const int l = mi * 16 + quad * 4 + reg;
                        const int cw = (l >> 1) ^ g4;
                        T[dl * 64 + cw * 2 + (l & 1)] = f2bf(acc[mi][ni][reg]);
                    }
            }
            #pragma unroll
            for (int s = 0; s < 4; s++) {
                const int dl = s * 8 + (lane >> 3);
                const int d  = p * 32 + dl;
                const int g4 = (dl & 7) << 2;
                const int pd = ((lane & 7) * 4) ^ g4;
                uint4 val = *(const uint4*)&T[dl * 64 + pd * 2];
                *(uint4*)&vT[((size_t)(b * NH + h) * HD + d) * LL + lg] = val;
            }
        }
    } else {
        unsigned short* dst = (which == 0) ? qws : kws;
        #pragma unroll
        for (int mi = 0; mi < 4; mi++) {
            #pragma unroll
            for (int reg = 0; reg < 4; reg++) {
                const int row = m0 + wm * 64 + mi * 16 + quad * 4 + reg;
                const int b = row >> 11, l = row & (LL - 1);
                #pragma unroll
                for (int ni = 0; ni < 4; ni++) {
                    const int d = ni * 16 + lr;
                    const float c = cosb[l * HD + d];
                    const float s = sinb[l * HD + d];
                    const float partner = (d < 32) ? -acc[mi][ni + 2][reg]
                                                   :  acc[mi][ni - 2][reg];
                    dst[((size_t)(b * NH + h) * LL + l) * HD + d] =
                        f2bf(acc[mi][ni][reg] * c + partner * s);
                }
            }
        }
    }
}

// ---------------------------------------------------------------------------
// Kernel 2: sliding-window attention. 4-wave block per 64 queries of one
// (b,h): K-span (320 keys) staged once in 40 KB LDS (chunk-swizzled), shared
// by all 4 waves (4x less K traffic). Scores live in registers (17 x f32x4);
// after one barrier the K region is REUSED as the bf16 P region (37.9 KB).
// exp at C-layout, rowsums via shfl butterfly, 1/sum folded into epilogue.
// LDS 40 KB -> exactly 4 blocks/CU; launch_bounds(256,4) caps VGPR at 128.
// ---------------------------------------------------------------------------
#define SW_SPAN 320
#define SSTRIDE 296   // u16; 16B-aligned rows
__global__ __launch_bounds__(256, 4) void swa_attn(
    const unsigned short* __restrict__ qws,
    const unsigned short* __restrict__ kws,
    const unsigned short* __restrict__ vT,
    unsigned short* __restrict__ aout)
{
    __shared__ __align__(16) unsigned short Ks[SW_SPAN * 64];  // 40 KB; later P

    const int t = threadIdx.x;
    const int lane = t & 63, w = t >> 6;
    const int qb = blockIdx.x, h = blockIdx.y, b = blockIdx.z;
    const int q0 = qb * 64;
    const int base_key = q0 - WIN;            // staging row 0 <-> this key

    const int lr = lane & 15, quad = lane >> 4, ko = quad * 8;
    const size_t base = ((size_t)(b * NH + h)) * LL * HD;
    const unsigned short* Q  = qws + base;
    const unsigned short* K  = kws + base;
    const unsigned short* VT = vT + base;     // [64][LL]

    // ---- stage K[320][64], 8-chunk swizzle: dst pos g holds src chunk g^(R&7)
    {
        const int rsub = t >> 3;              // 0..31
        const int csw  = (t & 7) ^ (rsub & 7);
        #pragma unroll
        for (int p = 0; p < 10; p++) {
            const int j = min(max(base_key + p * 32 + rsub, 0), LL - 1);
            gll16(K + (size_t)j * HD + csw * 8, &Ks[p * 2048 + t * 8]);
        }
    }
    const int i0 = q0 + w * 16;               // wave's query tile
    const bf16x8 qa0 = load8bf(Q + (size_t)(i0 + lr) * HD + ko);
    const bf16x8 qa1 = load8bf(Q + (size_t)(i0 + lr) * HD + 32 + ko);
    __syncthreads();

    // ---- scores from LDS K; exp'd into registers ----
    f32x4 sc[17];
    float rowsum[4] = {0.f, 0.f, 0.f, 0.f};
    #pragma unroll
    for (int kt = 0; kt < 17; kt++) {
        const int R = w * 16 + kt * 16 + lr;  // staging row = key index
        const bf16x8 kb0 = load8bf(&Ks[R * 64 + ((quad       ^ (R & 7)) * 8)]);
        const bf16x8 kb1 = load8bf(&Ks[R * 64 + (((quad + 4) ^ (R & 7)) * 8)]);
        f32x4 s = 0.0f;
        s = __builtin_amdgcn_mfma_f32_16x16x32_bf16(qa0, kb0, s, 0, 0, 0);
        s = __builtin_amdgcn_mfma_f32_16x16x32_bf16(qa1, kb1, s, 0, 0, 0);
        #pragma unroll
        for (int reg = 0; reg < 4; reg++) {
            const int i = i0 + quad * 4 + reg;
            const int j = base_key + w * 16 + kt * 16 + lr;
            const bool valid = (j >= 0) && (j <= i) && (j >= i - WIN);
            const float e = valid ? __expf(s[reg] * 0.125f) : 0.0f;
            rowsum[reg] += e;
            sc[kt][reg] = e;
        }
    }
    __syncthreads();                          // K region dead -> becomes P

    // ---- P (bf16, unnormalized) into reused LDS; wave-local region ----
    unsigned short* Pb = Ks + w * (16 * SSTRIDE);   // 9472 B/wave, 37.9 KB tot
    #pragma unroll
    for (int kt = 0; kt < 17; kt++)
        #pragma unroll
        for (int reg = 0; reg < 4; reg++)
            Pb[(quad * 4 + reg) * SSTRIDE + kt * 16 + lr] = f2bf(sc[kt][reg]);
    #pragma unroll
    for (int r = 0; r < 4; r++)               // zero-pad cols [272, 288)
        Pb[(quad * 4 + r) * SSTRIDE + 272 + lr] = 0;

    float inv[4];
    #pragma unroll
    for (int reg = 0; reg < 4; reg++) {       // 16-lane butterfly within quad
        float s = rowsum[reg];
        s += __shfl_xor(s, 1); s += __shfl_xor(s, 2);
        s += __shfl_xor(s, 4); s += __shfl_xor(s, 8);
        inv[reg] = 1.0f / s;
    }

    // ---- O = P @ V (V direct from global vT; wave-local LDS RAW via lgkmcnt)
    f32x4 o[4];
    #pragma unroll
    for (int nt = 0; nt < 4; nt++) o[nt] = 0.0f;

    #pragma unroll
    for (int kc = 0; kc < 9; kc++) {
        const bf16x8 pa = load8bf(&Pb[lr * SSTRIDE + kc * 32 + ko]);
        int kb = base_key + w * 16 + kc * 32 + ko;
        kb = min(max(kb, 0), LL - 8);         // clamp touches only P==0 cols
        bf16x8 bv[4];
        #pragma unroll
        for (int nt = 0; nt < 4; nt++)
            bv[nt] = load8bf(VT + (size_t)(nt * 16 + lr) * LL + kb);
        #pragma unroll
        for (int nt = 0; nt < 4; nt++)
            o[nt] = __builtin_amdgcn_mfma_f32_16x16x32_bf16(pa, bv[nt], o[nt], 0, 0, 0);
    }

    #pragma unroll
    for (int nt = 0; nt < 4; nt++) {
        #pragma unroll
        for (int reg = 0; reg < 4; reg++) {
            const int i = i0 + quad * 4 + reg;
            const int d = nt * 16 + lr;
            aout[((size_t)(b * LL + i)) * DIM + h * HD + d] =
                f2bf(o[nt][reg] * inv[reg]);
        }
    }
}

// ---------------------------------------------------------------------------
// Kernel 3: output projection. 128(M)x64(N) tiles -> 512 blocks, BK=32 +
// swizzled staging. Wave = 64M x 32N.
// ---------------------------------------------------------------------------
__global__ __launch_bounds__(256) void out_gemm(
    const unsigned short* __restrict__ A,
    const unsigned short* __restrict__ Wob,
    float* __restrict__ out)
{
    __shared__ __align__(16) unsigned short smem[128 * 32 + 64 * 32];  // 12 KB
    unsigned short* As = smem;
    unsigned short* Bs = smem + 128 * 32;
    const int t = threadIdx.x;
    const int lane = t & 63, w = t >> 6;
    const int wm = w >> 1, wn = w & 1;
    const int lr = lane & 15, quad = lane >> 4;
    const int n0 = blockIdx.x * 64, m0 = blockIdx.y * 128;

    f32x4 acc[4][2];
    for (int i = 0; i < 4; i++) for (int j = 0; j < 2; j++) acc[i][j] = 0.0f;

    const int arow = t >> 2;
    const int scol = (((t & 3) ^ ((t >> 3) & 3))) * 8;
    const unsigned short* ga = A   + (size_t)(m0 + arow) * DIM + scol;
    const unsigned short* gb = Wob + (size_t)(n0 + arow) * DIM + scol;
    unsigned short* la0 = &As[t * 8];
    unsigned short* la1 = &As[t * 8 + 2048];
    unsigned short* lb0 = &Bs[t * 8];

    const int sw = (lr >> 1) & 3;

    for (int k0 = 0; k0 < DIM; k0 += 32) {
        __syncthreads();
        gll16(ga + k0,            la0);
        gll16(ga + 64 * DIM + k0, la1);
        gll16(gb + k0,            lb0);
        __syncthreads();
        bf16x8 af[4], bfr[2];
        #pragma unroll
        for (int mi = 0; mi < 4; mi++)
            af[mi] = load8bf(&As[(wm * 64 + mi * 16 + lr) * 32 + (quad ^ sw) * 8]);
        #pragma unroll
        for (int ni = 0; ni < 2; ni++)
            bfr[ni] = load8bf(&Bs[(wn * 32 + ni * 16 + lr) * 32 + (quad ^ sw) * 8]);
        #pragma unroll
        for (int mi = 0; mi < 4; mi++)
            #pragma unroll
            for (int ni = 0; ni < 2; ni++)
                acc[mi][ni] = __builtin_amdgcn_mfma_f32_16x16x32_bf16(
                    af[mi], bfr[ni], acc[mi][ni], 0, 0, 0);
    }

    #pragma unroll
    for (int mi = 0; mi < 4; mi++) {
        #pragma unroll
        for (int reg = 0; reg < 4; reg++) {
            const int row = m0 + wm * 64 + mi * 16 + quad * 4 + reg;
            #pragma unroll
            for (int ni = 0; ni < 2; ni++) {
                const int col = n0 + wn * 32 + ni * 16 + lr;
                out[(size_t)row * DIM + col] = acc[mi][ni][reg];
            }
        }
    }
}

extern "C" void kernel_launch(void* const* d_in, const int* in_sizes, int n_in,
                              void* d_out, int out_size, void* d_ws, size_t ws_size,
                              hipStream_t stream)
{
    const float* x    = (const float*)d_in[0];
    const float* cosb = (const float*)d_in[1];
    const float* sinb = (const float*)d_in[2];
    const float* Wq   = (const float*)d_in[3];
    const float* Wk   = (const float*)d_in[4];
    const float* Wv   = (const float*)d_in[5];
    const float* Wo   = (const float*)d_in[6];
    float* out = (float*)d_out;

    unsigned short* xb   = (unsigned short*)d_ws;
    unsigned short* wqkv = xb + (size_t)MM * DIM;
    unsigned short* wob  = wqkv + (size_t)NQKV * DIM;
    unsigned short* qws  = wob + (size_t)DIM * DIM;
    unsigned short* kws  = qws + (size_t)BB * NH * LL * HD;
    unsigned short* vT   = kws + (size_t)BB * NH * LL * HD;
    unsigned short* aws  = xb;   // alias: xb dead after qkv_gemm

    convert_inputs<<<dim3(SEG / (256 * 8), 8), 256, 0, stream>>>(
        x, Wq, Wk, Wv, Wo, xb, wqkv, wob);
    qkv_gemm<<<dim3(NQKV / 128, MM / 128), 256, 0, stream>>>(
        xb, wqkv, cosb, sinb, qws, kws, vT);
    swa_attn<<<dim3(LL / 64, NH, BB), 256, 0, stream>>>(qws, kws, vT, aws);
    out_gemm<<<dim3(DIM / 64, MM / 128), 256, 0, stream>>>(aws, wob, out);
}

// Round 7
// 164.087 us; speedup vs baseline: 2.1542x; 1.1060x over previous
//
#include <hip/hip_runtime.h>

// SlidingWindowAttention: B=2, L=2048, D=1024, H=16, hd=64, W=256.
// I/O f32; internal bf16 MFMA with f32 accum.
#define DIM 1024
#define NH  16
#define HD  64
#define BB  2
#define LL  2048
#define WIN 256
#define MM  (BB * LL)     // 4096 rows
#define NQKV (3 * DIM)    // 3072 fused QKV output cols
#define SEG  (DIM * DIM)

typedef __bf16 bf16x8 __attribute__((ext_vector_type(8)));
typedef float  f32x4  __attribute__((ext_vector_type(4)));
typedef unsigned short u16x8 __attribute__((ext_vector_type(8)));

__device__ __forceinline__ unsigned short f2bf(float f) {
    union { float f; unsigned int i; } v; v.f = f;
    unsigned int r = v.i + 0x7fffu + ((v.i >> 16) & 1u);  // RNE
    return (unsigned short)(r >> 16);
}
__device__ __forceinline__ bf16x8 load8bf(const unsigned short* p) {
    uint4 u = *reinterpret_cast<const uint4*>(p);
    return __builtin_bit_cast(bf16x8, u);
}
__device__ __forceinline__ void gll16(const void* g, void* l) {
    __builtin_amdgcn_global_load_lds(
        (const __attribute__((address_space(1))) unsigned int*)g,
        (__attribute__((address_space(3))) unsigned int*)l, 16, 0, 0);
}

// ---------------------------------------------------------------------------
// Kernel 0: f32 -> bf16 conversion/packing.
// ---------------------------------------------------------------------------
__global__ __launch_bounds__(256) void convert_inputs(
    const float* __restrict__ x,
    const float* __restrict__ Wq, const float* __restrict__ Wk,
    const float* __restrict__ Wv, const float* __restrict__ Wo,
    unsigned short* __restrict__ xb,
    unsigned short* __restrict__ wqkv,
    unsigned short* __restrict__ wob)
{
    const int y = blockIdx.y;
    const size_t base = ((size_t)blockIdx.x * 256 + threadIdx.x) * 8;
    const float* src; unsigned short* dst;
    if (y < 4)       { src = x + (size_t)y * SEG;  dst = xb + (size_t)y * SEG; }
    else if (y == 4) { src = Wq; dst = wqkv; }
    else if (y == 5) { src = Wk; dst = wqkv + SEG; }
    else if (y == 6) { src = Wv; dst = wqkv + 2 * (size_t)SEG; }
    else             { src = Wo; dst = wob; }
    float4 a = ((const float4*)(src + base))[0];
    float4 b = ((const float4*)(src + base))[1];
    u16x8 r;
    r[0] = f2bf(a.x); r[1] = f2bf(a.y); r[2] = f2bf(a.z); r[3] = f2bf(a.w);
    r[4] = f2bf(b.x); r[5] = f2bf(b.y); r[6] = f2bf(b.z); r[7] = f2bf(b.w);
    *(u16x8*)(dst + base) = r;
}

// ---------------------------------------------------------------------------
// Kernel 1: fused QKV GEMM + RoPE. 128x128 tile, 4 waves (2x2), BK=64
// (16 K-iterations -> half the barrier drains of BK=32). launch_bounds(256,4)
// caps VGPR at 128 (round-4's 132-VGPR cliff was the BK=64 killer).
// 8-chunk XOR swizzle: LDS row R position g holds source chunk g^(R&7)
// -> conflict-free ds_read_b128 frags.
// q,k -> [B,H,L,64] (RoPE fused); v -> [B,H,64,L] via 2-pass LDS transpose.
// ---------------------------------------------------------------------------
__global__ __launch_bounds__(256, 4) void qkv_gemm(
    const unsigned short* __restrict__ xb,
    const unsigned short* __restrict__ wqkv,
    const float* __restrict__ cosb, const float* __restrict__ sinb,
    unsigned short* __restrict__ qws, unsigned short* __restrict__ kws,
    unsigned short* __restrict__ vT)
{
    __shared__ __align__(16) unsigned short smem[2 * 128 * 64];  // As|Bs 32 KB
    unsigned short* As = smem;
    unsigned short* Bs = smem + 128 * 64;
    const int t = threadIdx.x;
    const int lane = t & 63, w = t >> 6;
    const int wm = w >> 1, wn = w & 1;
    const int lr = lane & 15, quad = lane >> 4;
    const int n0 = blockIdx.x * 128, m0 = blockIdx.y * 128;

    f32x4 acc[4][4];
    for (int i = 0; i < 4; i++) for (int j = 0; j < 4; j++) acc[i][j] = 0.0f;

    const int rsub = t >> 3;                 // 0..31
    const int csw  = (t & 7) ^ (rsub & 7);   // swizzled source chunk
    const int sw7  = lr & 7;                 // frag-read swizzle key

    for (int k0 = 0; k0 < DIM; k0 += 64) {
        __syncthreads();
        #pragma unroll
        for (int p = 0; p < 4; p++) {
            const int row = p * 32 + rsub;
            gll16(xb   + (size_t)(m0 + row) * DIM + k0 + csw * 8,
                  &As[p * 2048 + t * 8]);
            gll16(wqkv + (size_t)(n0 + row) * DIM + k0 + csw * 8,
                  &Bs[p * 2048 + t * 8]);
        }
        __syncthreads();
        #pragma unroll
        for (int kk = 0; kk < 2; kk++) {
            bf16x8 af[4], bfr[4];
            #pragma unroll
            for (int mi = 0; mi < 4; mi++) {
                const int R = wm * 64 + mi * 16 + lr;
                af[mi] = load8bf(&As[R * 64 + (((kk * 4 + quad) ^ sw7) * 8)]);
            }
            #pragma unroll
            for (int ni = 0; ni < 4; ni++) {
                const int R = wn * 64 + ni * 16 + lr;
                bfr[ni] = load8bf(&Bs[R * 64 + (((kk * 4 + quad) ^ sw7) * 8)]);
            }
            #pragma unroll
            for (int mi = 0; mi < 4; mi++)
                #pragma unroll
                for (int ni = 0; ni < 4; ni++)
                    acc[mi][ni] = __builtin_amdgcn_mfma_f32_16x16x32_bf16(
                        af[mi], bfr[ni], acc[mi][ni], 0, 0, 0);
        }
    }

    const int ng = n0 + wn * 64;
    const int which = ng >> 10;            // 0=q 1=k 2=v (block-uniform)
    const int h = (ng & (DIM - 1)) >> 6;

    if (which == 2) {
        // ---- v: transpose 64x64 tile -> vT[B,H,64,L], 2 passes of 32 d-rows
        __syncthreads();
        unsigned short* T = smem + w * 2048;
        const int token0 = m0 + wm * 64;
        const int b  = token0 >> 11;
        const int lg = (token0 & (LL - 1)) + (lane & 7) * 8;
        #pragma unroll
        for (int p = 0; p < 2; p++) {
            #pragma unroll
            for (int ni = 2 * p; ni < 2 * p + 2; ni++) {
                const int dl = (ni & 1) * 16 + lr;
                const int g4 = (dl & 7) << 2;
                #pragma unroll
                for (int mi = 0; mi < 4; mi++)
                    #pragma unroll
                    for (int reg = 0; reg < 4; reg++) {
                        const int l = mi * 16 + quad * 4 + reg;
                        const int cw = (l >> 1) ^ g4;
                        T[dl * 64 + cw * 2 + (l & 1)] = f2bf(acc[mi][ni][reg]);
                    }
            }
            #pragma unroll
            for (int s = 0; s < 4; s++) {
                const int dl = s * 8 + (lane >> 3);
                const int d  = p * 32 + dl;
                const int g4 = (dl & 7) << 2;
                const int pd = ((lane & 7) * 4) ^ g4;
                uint4 val = *(const uint4*)&T[dl * 64 + pd * 2];
                *(uint4*)&vT[((size_t)(b * NH + h) * HD + d) * LL + lg] = val;
            }
        }
    } else {
        unsigned short* dst = (which == 0) ? qws : kws;
        #pragma unroll
        for (int mi = 0; mi < 4; mi++) {
            #pragma unroll
            for (int reg = 0; reg < 4; reg++) {
                const int row = m0 + wm * 64 + mi * 16 + quad * 4 + reg;
                const int b = row >> 11, l = row & (LL - 1);
                #pragma unroll
                for (int ni = 0; ni < 4; ni++) {
                    const int d = ni * 16 + lr;
                    const float c = cosb[l * HD + d];
                    const float s = sinb[l * HD + d];
                    const float partner = (d < 32) ? -acc[mi][ni + 2][reg]
                                                   :  acc[mi][ni - 2][reg];
                    dst[((size_t)(b * NH + h) * LL + l) * HD + d] =
                        f2bf(acc[mi][ni][reg] * c + partner * s);
                }
            }
        }
    }
}

// ---------------------------------------------------------------------------
// Kernel 2: sliding-window attention. 4-wave block per 64 queries of one
// (b,h): K-span (320 keys) staged once in 40 KB LDS (chunk-swizzled), shared
// by all 4 waves. Scores in registers; K region reused as bf16 P region.
// exp at C-layout, rowsums via shfl butterfly, 1/sum folded into epilogue.
// ---------------------------------------------------------------------------
#define SW_SPAN 320
#define SSTRIDE 296   // u16; 16B-aligned rows
__global__ __launch_bounds__(256, 4) void swa_attn(
    const unsigned short* __restrict__ qws,
    const unsigned short* __restrict__ kws,
    const unsigned short* __restrict__ vT,
    unsigned short* __restrict__ aout)
{
    __shared__ __align__(16) unsigned short Ks[SW_SPAN * 64];  // 40 KB; later P

    const int t = threadIdx.x;
    const int lane = t & 63, w = t >> 6;
    const int qb = blockIdx.x, h = blockIdx.y, b = blockIdx.z;
    const int q0 = qb * 64;
    const int base_key = q0 - WIN;

    const int lr = lane & 15, quad = lane >> 4, ko = quad * 8;
    const size_t base = ((size_t)(b * NH + h)) * LL * HD;
    const unsigned short* Q  = qws + base;
    const unsigned short* K  = kws + base;
    const unsigned short* VT = vT + base;     // [64][LL]

    {
        const int rsub = t >> 3;
        const int csw  = (t & 7) ^ (rsub & 7);
        #pragma unroll
        for (int p = 0; p < 10; p++) {
            const int j = min(max(base_key + p * 32 + rsub, 0), LL - 1);
            gll16(K + (size_t)j * HD + csw * 8, &Ks[p * 2048 + t * 8]);
        }
    }
    const int i0 = q0 + w * 16;
    const bf16x8 qa0 = load8bf(Q + (size_t)(i0 + lr) * HD + ko);
    const bf16x8 qa1 = load8bf(Q + (size_t)(i0 + lr) * HD + 32 + ko);
    __syncthreads();

    f32x4 sc[17];
    float rowsum[4] = {0.f, 0.f, 0.f, 0.f};
    #pragma unroll
    for (int kt = 0; kt < 17; kt++) {
        const int R = w * 16 + kt * 16 + lr;
        const bf16x8 kb0 = load8bf(&Ks[R * 64 + ((quad       ^ (R & 7)) * 8)]);
        const bf16x8 kb1 = load8bf(&Ks[R * 64 + (((quad + 4) ^ (R & 7)) * 8)]);
        f32x4 s = 0.0f;
        s = __builtin_amdgcn_mfma_f32_16x16x32_bf16(qa0, kb0, s, 0, 0, 0);
        s = __builtin_amdgcn_mfma_f32_16x16x32_bf16(qa1, kb1, s, 0, 0, 0);
        #pragma unroll
        for (int reg = 0; reg < 4; reg++) {
            const int i = i0 + quad * 4 + reg;
            const int j = base_key + w * 16 + kt * 16 + lr;
            const bool valid = (j >= 0) && (j <= i) && (j >= i - WIN);
            const float e = valid ? __expf(s[reg] * 0.125f) : 0.0f;
            rowsum[reg] += e;
            sc[kt][reg] = e;
        }
    }
    __syncthreads();                          // K region dead -> becomes P

    unsigned short* Pb = Ks + w * (16 * SSTRIDE);
    #pragma unroll
    for (int kt = 0; kt < 17; kt++)
        #pragma unroll
        for (int reg = 0; reg < 4; reg++)
            Pb[(quad * 4 + reg) * SSTRIDE + kt * 16 + lr] = f2bf(sc[kt][reg]);
    #pragma unroll
    for (int r = 0; r < 4; r++)
        Pb[(quad * 4 + r) * SSTRIDE + 272 + lr] = 0;

    float inv[4];
    #pragma unroll
    for (int reg = 0; reg < 4; reg++) {
        float s = rowsum[reg];
        s += __shfl_xor(s, 1); s += __shfl_xor(s, 2);
        s += __shfl_xor(s, 4); s += __shfl_xor(s, 8);
        inv[reg] = 1.0f / s;
    }

    f32x4 o[4];
    #pragma unroll
    for (int nt = 0; nt < 4; nt++) o[nt] = 0.0f;

    #pragma unroll
    for (int kc = 0; kc < 9; kc++) {
        const bf16x8 pa = load8bf(&Pb[lr * SSTRIDE + kc * 32 + ko]);
        int kb = base_key + w * 16 + kc * 32 + ko;
        kb = min(max(kb, 0), LL - 8);
        bf16x8 bv[4];
        #pragma unroll
        for (int nt = 0; nt < 4; nt++)
            bv[nt] = load8bf(VT + (size_t)(nt * 16 + lr) * LL + kb);
        #pragma unroll
        for (int nt = 0; nt < 4; nt++)
            o[nt] = __builtin_amdgcn_mfma_f32_16x16x32_bf16(pa, bv[nt], o[nt], 0, 0, 0);
    }

    #pragma unroll
    for (int nt = 0; nt < 4; nt++) {
        #pragma unroll
        for (int reg = 0; reg < 4; reg++) {
            const int i = i0 + quad * 4 + reg;
            const int d = nt * 16 + lr;
            aout[((size_t)(b * LL + i)) * DIM + h * HD + d] =
                f2bf(o[nt][reg] * inv[reg]);
        }
    }
}

// ---------------------------------------------------------------------------
// Kernel 3: output projection. 128(M)x64(N) tiles, BK=64 (16 barriers),
// swizzled staging, launch_bounds(256,4). Wave = 64M x 32N.
// ---------------------------------------------------------------------------
__global__ __launch_bounds__(256, 4) void out_gemm(
    const unsigned short* __restrict__ A,
    const unsigned short* __restrict__ Wob,
    float* __restrict__ out)
{
    __shared__ __align__(16) unsigned short smem[128 * 64 + 64 * 64];  // 24 KB
    unsigned short* As = smem;
    unsigned short* Bs = smem + 128 * 64;
    const int t = threadIdx.x;
    const int lane = t & 63, w = t >> 6;
    const int wm = w >> 1, wn = w & 1;
    const int lr = lane & 15, quad = lane >> 4;
    const int n0 = blockIdx.x * 64, m0 = blockIdx.y * 128;

    f32x4 acc[4][2];
    for (int i = 0; i < 4; i++) for (int j = 0; j < 2; j++) acc[i][j] = 0.0f;

    const int rsub = t >> 3;
    const int csw  = (t & 7) ^ (rsub & 7);
    const int sw7  = lr & 7;

    for (int k0 = 0; k0 < DIM; k0 += 64) {
        __syncthreads();
        #pragma unroll
        for (int p = 0; p < 4; p++) {
            const int row = p * 32 + rsub;
            gll16(A + (size_t)(m0 + row) * DIM + k0 + csw * 8,
                  &As[p * 2048 + t * 8]);
        }
        #pragma unroll
        for (int p = 0; p < 2; p++) {
            const int row = p * 32 + rsub;
            gll16(Wob + (size_t)(n0 + row) * DIM + k0 + csw * 8,
                  &Bs[p * 2048 + t * 8]);
        }
        __syncthreads();
        #pragma unroll
        for (int kk = 0; kk < 2; kk++) {
            bf16x8 af[4], bfr[2];
            #pragma unroll
            for (int mi = 0; mi < 4; mi++) {
                const int R = wm * 64 + mi * 16 + lr;
                af[mi] = load8bf(&As[R * 64 + (((kk * 4 + quad) ^ sw7) * 8)]);
            }
            #pragma unroll
            for (int ni = 0; ni < 2; ni++) {
                const int R = wn * 32 + ni * 16 + lr;
                bfr[ni] = load8bf(&Bs[R * 64 + (((kk * 4 + quad) ^ sw7) * 8)]);
            }
            #pragma unroll
            for (int mi = 0; mi < 4; mi++)
                #pragma unroll
                for (int ni = 0; ni < 2; ni++)
                    acc[mi][ni] = __builtin_amdgcn_mfma_f32_16x16x32_bf16(
                        af[mi], bfr[ni], acc[mi][ni], 0, 0, 0);
        }
    }

    #pragma unroll
    for (int mi = 0; mi < 4; mi++) {
        #pragma unroll
        for (int reg = 0; reg < 4; reg++) {
            const int row = m0 + wm * 64 + mi * 16 + quad * 4 + reg;
            #pragma unroll
            for (int ni = 0; ni < 2; ni++) {
                const int col = n0 + wn * 32 + ni * 16 + lr;
                out[(size_t)row * DIM + col] = acc[mi][ni][reg];
            }
        }
    }
}

extern "C" void kernel_launch(void* const* d_in, const int* in_sizes, int n_in,
                              void* d_out, int out_size, void* d_ws, size_t ws_size,
                              hipStream_t stream)
{
    const float* x    = (const float*)d_in[0];
    const float* cosb = (const float*)d_in[1];
    const float* sinb = (const float*)d_in[2];
    const float* Wq   = (const float*)d_in[3];
    const float* Wk   = (const float*)d_in[4];
    const float* Wv   = (const float*)d_in[5];
    const float* Wo   = (const float*)d_in[6];
    float* out = (float*)d_out;

    unsigned short* xb   = (unsigned short*)d_ws;
    unsigned short* wqkv = xb + (size_t)MM * DIM;
    unsigned short* wob  = wqkv + (size_t)NQKV * DIM;
    unsigned short* qws  = wob + (size_t)DIM * DIM;
    unsigned short* kws  = qws + (size_t)BB * NH * LL * HD;
    unsigned short* vT   = kws + (size_t)BB * NH * LL * HD;
    unsigned short* aws  = xb;   // alias: xb dead after qkv_gemm

    convert_inputs<<<dim3(SEG / (256 * 8), 8), 256, 0, stream>>>(
        x, Wq, Wk, Wv, Wo, xb, wqkv, wob);
    qkv_gemm<<<dim3(NQKV / 128, MM / 128), 256, 0, stream>>>(
        xb, wqkv, cosb, sinb, qws, kws, vT);
    swa_attn<<<dim3(LL / 64, NH, BB), 256, 0, stream>>>(qws, kws, vT, aws);
    out_gemm<<<dim3(DIM / 64, MM / 128), 256, 0, stream>>>(aws, wob, out);
}